// Round 14
// baseline (4915.921 us; speedup 1.0000x reference)
//
#include <hip/hip_runtime.h>
#include <math.h>

// Problem constants (fixed by the reference module)
#define HSZ   512
#define H4    2048
#define SEQ   64
#define VOC   32000
#define BEAM  3
#define TMAX  50
#define FLS   16   // flag line stride in ints (64 B)

#define LOFF  ((size_t)H4 * HSZ)   // per-layer weight stride

__device__ __forceinline__ float wsum(float v) {
#pragma unroll
  for (int off = 32; off; off >>= 1) v += __shfl_xor(v, off, 64);
  return v;
}
__device__ __forceinline__ float dot4(float4 a, float4 b) {
  return a.x * b.x + a.y * b.y + a.z * b.z + a.w * b.w;
}
__device__ __forceinline__ float sigf(float x) { return 1.f / (1.f + expf(-x)); }

__device__ __forceinline__ bool better(float v1, int i1, float v2, int i2) {
  return (v1 > v2) || (v1 == v2 && i1 < i2);  // jax.lax.top_k order: value desc, index asc
}
__device__ __forceinline__ void ins3(float* v, int* idx, float nv, int ni) {
  if (better(nv, ni, v[2], idx[2])) {
    if (better(nv, ni, v[1], idx[1])) {
      v[2] = v[1]; idx[2] = idx[1];
      if (better(nv, ni, v[0], idx[0])) { v[1] = v[0]; idx[1] = idx[0]; v[0] = nv; idx[0] = ni; }
      else { v[1] = nv; idx[1] = ni; }
    } else { v[2] = nv; idx[2] = ni; }
  }
}

// coherent accessors (agent scope, relaxed) — validated bit-exact rounds 5-12
__device__ __forceinline__ float agld(const float* p) {
  return __hip_atomic_load(p, __ATOMIC_RELAXED, __HIP_MEMORY_SCOPE_AGENT);
}
__device__ __forceinline__ void agst(float* p, float v) {
  __hip_atomic_store(p, v, __ATOMIC_RELAXED, __HIP_MEMORY_SCOPE_AGENT);
}
__device__ __forceinline__ int agldi(const int* p) {
  return __hip_atomic_load(p, __ATOMIC_RELAXED, __HIP_MEMORY_SCOPE_AGENT);
}

// ---------------- encoder ----------------

__global__ void __launch_bounds__(512) k_xw1(const float* __restrict__ Wih,
                                             const float* __restrict__ bias,
                                             const float* __restrict__ emb,
                                             const int* __restrict__ seq,
                                             float* __restrict__ xp1) {
  int t    = threadIdx.x & 63;
  int wave = threadIdx.x >> 6;
  int r    = blockIdx.x * 8 + wave;
  int tok  = seq[t];
  const float* xr = emb + (size_t)tok * HSZ;
  const float* wr = Wih + (size_t)r * HSZ;
  float acc = 0.f;
  for (int e = 0; e < HSZ; e += 4) {
    float4 wv = *(const float4*)(wr + e);
    float4 xv = *(const float4*)(xr + e);
    acc += dot4(wv, xv);
  }
  xp1[t * H4 + r] = acc + bias[r];
}

__global__ void __launch_bounds__(512) k_encslot(const float* __restrict__ Whh1,
                                                 const float* __restrict__ Wih2,
                                                 const float* __restrict__ Whh2,
                                                 const float* __restrict__ b2,
                                                 const float* __restrict__ xp1,
                                                 float* __restrict__ h1a, float* __restrict__ c1a,
                                                 float* __restrict__ h2a, float* __restrict__ c2a,
                                                 int s) {
  __shared__ float rowX[HSZ], rowH[HSZ], zl[16];
  int tid = threadIdx.x, wave = tid >> 6, lane = tid & 63;
  bool l2 = blockIdx.x >= 128;
  int t = l2 ? s - 1 : s;
  if (t < 0 || t >= SEQ) return;
  int bb = blockIdx.x & 127;
  int lr = wave >> 1;
  int j  = bb * 4 + lr;
  int g0 = (wave & 1) * 2;
  if (!l2) {
    rowX[tid] = (t > 0) ? h1a[t * HSZ + tid] : 0.f;
    __syncthreads();
    float4 h0 = ((const float4*)rowX)[lane], h1v = ((const float4*)rowX)[lane + 64];
#pragma unroll
    for (int gg = 0; gg < 2; ++gg) {
      int g = g0 + gg;
      int row = j + (g << 9);
      const float4* wr = (const float4*)(Whh1 + (size_t)row * HSZ);
      float zs = wsum(dot4(wr[lane], h0) + dot4(wr[lane + 64], h1v));
      if (lane == 0) zl[lr * 4 + g] = zs + xp1[t * H4 + row];
    }
    __syncthreads();
    if (tid < 4) {
      int j2 = bb * 4 + tid;
      float z0 = zl[tid * 4 + 0], z1 = zl[tid * 4 + 1], z2 = zl[tid * 4 + 2], z3 = zl[tid * 4 + 3];
      float cp = (t > 0) ? c1a[t * HSZ + j2] : 0.f;
      float c = sigf(z1) * cp + sigf(z0) * tanhf(z2);
      c1a[(t + 1) * HSZ + j2] = c;
      h1a[(t + 1) * HSZ + j2] = sigf(z3) * tanhf(c);
    }
  } else {
    rowX[tid] = h1a[(t + 1) * HSZ + tid];
    rowH[tid] = (t > 0) ? h2a[t * HSZ + tid] : 0.f;
    __syncthreads();
    float4 x0 = ((const float4*)rowX)[lane], x1 = ((const float4*)rowX)[lane + 64];
    float4 h0 = ((const float4*)rowH)[lane], h1v = ((const float4*)rowH)[lane + 64];
#pragma unroll
    for (int gg = 0; gg < 2; ++gg) {
      int g = g0 + gg;
      int row = j + (g << 9);
      const float4* wi = (const float4*)(Wih2 + (size_t)row * HSZ);
      const float4* wh = (const float4*)(Whh2 + (size_t)row * HSZ);
      float zs = wsum(dot4(wi[lane], x0) + dot4(wi[lane + 64], x1) +
                      dot4(wh[lane], h0) + dot4(wh[lane + 64], h1v));
      if (lane == 0) zl[lr * 4 + g] = zs + b2[row];
    }
    __syncthreads();
    if (tid < 4) {
      int j2 = bb * 4 + tid;
      float z0 = zl[tid * 4 + 0], z1 = zl[tid * 4 + 1], z2 = zl[tid * 4 + 2], z3 = zl[tid * 4 + 3];
      float cp = (t > 0) ? c2a[t * HSZ + j2] : 0.f;
      float c = sigf(z1) * cp + sigf(z0) * tanhf(z2);
      c2a[(t + 1) * HSZ + j2] = c;
      h2a[(t + 1) * HSZ + j2] = sigf(z3) * tanhf(c);
    }
  }
}

// ---------------- decoder ----------------

// Layer-1 cell with FUSED beam merge over 256 partial sets (r11 verbatim).
template <int B, int BIN, int MODE>
__global__ void __launch_bounds__(512) k_dcell1(
    const float* __restrict__ Wih, const float* __restrict__ Whh,
    const float* __restrict__ bias,
    const float* __restrict__ emb_dec, const int* __restrict__ bosp,
    const float* __restrict__ h1prev, const float* __restrict__ c1prev,
    const float* __restrict__ h2prev, const float* __restrict__ c2prev,
    const float* __restrict__ pm, const float* __restrict__ ps,
    const float* __restrict__ pv, const int* __restrict__ pi,
    float* __restrict__ hout, float* __restrict__ cout,
    float* __restrict__ hd2p, float* __restrict__ cd2p,
    const float* __restrict__ scores_rd, float* __restrict__ scores_wr,
    const int* __restrict__ tokens_rd, int* __restrict__ tokens_wr,
    int* __restrict__ bt, int ti) {
  __shared__ float xl[B * HSZ], hl[B * HSZ], cl[B * HSZ], zl[8 * B];
  __shared__ float sM[3], sS[3], sV[3][3], sScore[3];
  __shared__ int sI[3][3], sOrig[3], sTokNew[3], sTokOld[3];
  int tid = threadIdx.x, wave = tid >> 6, lane = tid & 63;

  if (MODE >= 1) {
    if (wave < BIN) {
      int b = wave;
      float lm4[4], ls4[4];
      float M = -INFINITY;
#pragma unroll
      for (int q = 0; q < 4; ++q) {
        int blk2 = lane + q * 64;
        lm4[q] = pm[blk2 * 3 + b]; ls4[q] = ps[blk2 * 3 + b];
        M = fmaxf(M, lm4[q]);
      }
#pragma unroll
      for (int off = 32; off; off >>= 1) M = fmaxf(M, __shfl_xor(M, off, 64));
      float S = 0.f;
#pragma unroll
      for (int q = 0; q < 4; ++q) S += (ls4[q] == 0.f) ? 0.f : ls4[q] * expf(lm4[q] - M);
      S = wsum(S);
      float bv[3] = {-INFINITY, -INFINITY, -INFINITY};
      int bi3[3]  = {0x7fffffff, 0x7fffffff, 0x7fffffff};
#pragma unroll
      for (int q = 0; q < 4; ++q) {
        int blk2 = lane + q * 64;
#pragma unroll
        for (int k = 0; k < 3; ++k)
          ins3(bv, bi3, pv[(blk2 * 3 + b) * 3 + k], pi[(blk2 * 3 + b) * 3 + k]);
      }
#pragma unroll
      for (int off = 32; off; off >>= 1) {
        float ov[3]; int oi[3];
#pragma unroll
        for (int k = 0; k < 3; ++k) { ov[k] = __shfl_xor(bv[k], off, 64); oi[k] = __shfl_xor(bi3[k], off, 64); }
#pragma unroll
        for (int k = 0; k < 3; ++k) ins3(bv, bi3, ov[k], oi[k]);
      }
      if (lane == 0) {
        sM[b] = M; sS[b] = S;
#pragma unroll
        for (int k = 0; k < 3; ++k) { sV[b][k] = bv[k]; sI[b][k] = bi3[k]; }
      }
    }
    __syncthreads();
    if (tid == 0) {
      if (MODE == 1) {
        float off0 = -sM[0] - logf(sS[0]);
        for (int k = 0; k < 3; ++k) {
          sScore[k] = sV[0][k] + off0;
          sTokNew[k] = sI[0][k]; sOrig[k] = 0; sTokOld[k] = 0;
        }
      } else {
        float osc[3];
        for (int b = 0; b < 3; ++b) { osc[b] = scores_rd[b]; sTokOld[b] = tokens_rd[b]; }
        float cum[9];
        for (int b = 0; b < 3; ++b) {
          float o = osc[b] - sM[b] - logf(sS[b]);
          for (int k = 0; k < 3; ++k) cum[b * 3 + k] = sV[b][k] + o;
        }
        bool used[9] = {false, false, false, false, false, false, false, false, false};
        for (int k = 0; k < 3; ++k) {
          int bf = 0; float bb = -INFINITY;
          for (int f = 0; f < 9; ++f)
            if (!used[f] && cum[f] > bb) { bb = cum[f]; bf = f; }  // strict >: lowest flat idx on tie
          used[bf] = true;
          sScore[k] = bb;
          int ob = bf / 3;
          sOrig[k] = ob;
          sTokNew[k] = sI[ob][bf - ob * 3];
        }
      }
    }
    __syncthreads();
  }

  if (MODE == 0) {
    int bos = bosp[0];
    for (int i = tid; i < B * HSZ; i += 512) {
      xl[i] = emb_dec[(size_t)bos * HSZ + i];
      hl[i] = h1prev[i]; cl[i] = c1prev[i];
    }
    if (blockIdx.x == 0) {
      for (int i = tid; i < B * HSZ; i += 512) { hd2p[i] = h2prev[i]; cd2p[i] = c2prev[i]; }
    }
  } else {
    for (int i = tid; i < B * HSZ; i += 512) {
      int b = i >> 9, e = i & 511;
      xl[i] = emb_dec[(size_t)sTokNew[b] * HSZ + e];
      hl[i] = h1prev[sOrig[b] * HSZ + e];
      cl[i] = c1prev[sOrig[b] * HSZ + e];
    }
    if (blockIdx.x == 0) {
      for (int i = tid; i < B * HSZ; i += 512) {
        int b = i >> 9, e = i & 511;
        hd2p[i] = h2prev[sOrig[b] * HSZ + e];
        cd2p[i] = c2prev[sOrig[b] * HSZ + e];
      }
      if (MODE == 1) {
        int bos = bosp[0];
        for (int idx = tid; idx < BEAM * TMAX; idx += 512) bt[idx] = bos;  // buffer 0
      } else {
        const int* src = bt + (ti & 1) * (BEAM * TMAX);
        int* dst = bt + ((ti + 1) & 1) * (BEAM * TMAX);
        for (int idx = tid; idx < BEAM * TMAX; idx += 512) {
          int k = idx / TMAX, jj = idx % TMAX, o = sOrig[k];
          dst[idx] = (jj == ti + 1) ? sTokOld[o] : src[o * TMAX + jj];
        }
      }
      if (tid < 3) { scores_wr[tid] = sScore[tid]; tokens_wr[tid] = sTokNew[tid]; }
    }
  }
  __syncthreads();

  int lr = wave >> 2;
  int g  = wave & 3;
  int j  = blockIdx.x * 2 + lr;
  int row = j + (g << 9);
  const float4* wi = (const float4*)(Wih + (size_t)row * HSZ);
  const float4* wh = (const float4*)(Whh + (size_t)row * HSZ);
  float4 wi0 = wi[lane], wi1 = wi[lane + 64], wh0 = wh[lane], wh1 = wh[lane + 64];
  float bb = bias[row];
#pragma unroll
  for (int b = 0; b < B; ++b) {
    float4 xv0 = ((const float4*)(xl + b * HSZ))[lane];
    float4 xv1 = ((const float4*)(xl + b * HSZ))[lane + 64];
    float4 hv0 = ((const float4*)(hl + b * HSZ))[lane];
    float4 hv1 = ((const float4*)(hl + b * HSZ))[lane + 64];
    float acc = dot4(wi0, xv0) + dot4(wi1, xv1) + dot4(wh0, hv0) + dot4(wh1, hv1);
    float z = wsum(acc) + bb;
    if (lane == 0) zl[(lr * 4 + g) * B + b] = z;
  }
  __syncthreads();
  for (int q = tid; q < 2 * B; q += 512) {
    int lr2 = q / B, b = q % B;
    int j2 = blockIdx.x * 2 + lr2;
    float z0 = zl[(lr2 * 4 + 0) * B + b], z1 = zl[(lr2 * 4 + 1) * B + b];
    float z2 = zl[(lr2 * 4 + 2) * B + b], z3 = zl[(lr2 * 4 + 3) * B + b];
    float c = sigf(z1) * cl[b * HSZ + j2] + sigf(z0) * tanhf(z2);
    cout[b * HSZ + j2] = c;
    hout[b * HSZ + j2] = sigf(z3) * tanhf(c);
  }
}

// layer-2 cell
template <int B>
__global__ void __launch_bounds__(512) k_dcell2(const float* __restrict__ Wih,
                                                const float* __restrict__ Whh,
                                                const float* __restrict__ bias,
                                                const float* __restrict__ x,
                                                const float* __restrict__ hin,
                                                const float* __restrict__ cin,
                                                float* __restrict__ hout, float* __restrict__ cout) {
  __shared__ float xl[B * HSZ], hl[B * HSZ], cl[B * HSZ], zl[8 * B];
  int tid = threadIdx.x;
  for (int i = tid; i < B * HSZ; i += 512) { xl[i] = x[i]; hl[i] = hin[i]; cl[i] = cin[i]; }
  __syncthreads();
  int wave = tid >> 6, lane = tid & 63;
  int lr = wave >> 2;
  int g  = wave & 3;
  int j  = blockIdx.x * 2 + lr;
  int row = j + (g << 9);
  const float4* wi = (const float4*)(Wih + (size_t)row * HSZ);
  const float4* wh = (const float4*)(Whh + (size_t)row * HSZ);
  float4 wi0 = wi[lane], wi1 = wi[lane + 64], wh0 = wh[lane], wh1 = wh[lane + 64];
  float bb = bias[row];
#pragma unroll
  for (int b = 0; b < B; ++b) {
    float4 xv0 = ((const float4*)(xl + b * HSZ))[lane];
    float4 xv1 = ((const float4*)(xl + b * HSZ))[lane + 64];
    float4 hv0 = ((const float4*)(hl + b * HSZ))[lane];
    float4 hv1 = ((const float4*)(hl + b * HSZ))[lane + 64];
    float acc = dot4(wi0, xv0) + dot4(wi1, xv1) + dot4(wh0, hv0) + dot4(wh1, hv1);
    float z = wsum(acc) + bb;
    if (lane == 0) zl[(lr * 4 + g) * B + b] = z;
  }
  __syncthreads();
  for (int q = tid; q < 2 * B; q += 512) {
    int lr2 = q / B, b = q % B;
    int j2 = blockIdx.x * 2 + lr2;
    float z0 = zl[(lr2 * 4 + 0) * B + b], z1 = zl[(lr2 * 4 + 1) * B + b];
    float z2 = zl[(lr2 * 4 + 2) * B + b], z3 = zl[(lr2 * 4 + 3) * B + b];
    float c = sigf(z1) * cl[b * HSZ + j2] + sigf(z0) * tanhf(z2);
    cout[b * HSZ + j2] = c;
    hout[b * HSZ + j2] = sigf(z3) * tanhf(c);
  }
}

// FUSED attfeat (blocks 0..63) -> counter sync -> logits with 4-lane-groups per row.
// Blocks 0..249 cover rows exactly (250*512/4 = 32000); blocks 250..255 emit neutral partials.
template <int B>
__global__ void __launch_bounds__(512) k_atlg2(const float* __restrict__ h2,
                                               const float* __restrict__ enc,
                                               const float* __restrict__ Wc,
                                               const float* __restrict__ Wout,
                                               const float* __restrict__ bout,
                                               float* __restrict__ feat,
                                               float* __restrict__ pm, float* __restrict__ ps,
                                               float* __restrict__ pv, int* __restrict__ pi,
                                               int* __restrict__ cnt, int ep) {
  __shared__ float xs[BEAM * HSZ], at[BEAM * SEQ], xcs[BEAM * 1024];
  __shared__ float fst[BEAM * HSZ];
  int tid = threadIdx.x, wave = tid >> 6, lane = tid & 63;

  if (blockIdx.x < 64) {  // producer: attention + context + feat (verbatim r11/r12)
    for (int i = tid; i < B * HSZ; i += 512) xs[i] = h2[i];
    __syncthreads();
    if (tid < B * SEQ) {
      int b = tid >> 6, s2 = tid & 63;
      const float* er = enc + (s2 + 1) * HSZ;
      const float* xb = xs + b * HSZ;
      float acc = 0.f;
      for (int e = 0; e < HSZ; e += 4) {
        float4 ev = *(const float4*)(er + e);
        acc += ev.x * xb[e] + ev.y * xb[e + 1] + ev.z * xb[e + 2] + ev.w * xb[e + 3];
      }
      at[tid] = acc;
    }
    __syncthreads();
    if (tid < B) {
      float m = -INFINITY;
      for (int s2 = 0; s2 < SEQ; ++s2) m = fmaxf(m, at[tid * SEQ + s2]);
      float s = 0.f;
      for (int s2 = 0; s2 < SEQ; ++s2) { float e = expf(at[tid * SEQ + s2] - m); at[tid * SEQ + s2] = e; s += e; }
      float inv = 1.f / s;
      for (int s2 = 0; s2 < SEQ; ++s2) at[tid * SEQ + s2] *= inv;
    }
    __syncthreads();
    if (tid < 128) {
      int h4 = tid * 4;
      float4 acc[B];
#pragma unroll
      for (int b = 0; b < B; ++b) acc[b] = make_float4(0.f, 0.f, 0.f, 0.f);
      for (int s2 = 0; s2 < SEQ; ++s2) {
        float4 ev = *(const float4*)(enc + (s2 + 1) * HSZ + h4);
#pragma unroll
        for (int b = 0; b < B; ++b) {
          float a = at[b * SEQ + s2];
          acc[b].x += a * ev.x; acc[b].y += a * ev.y; acc[b].z += a * ev.z; acc[b].w += a * ev.w;
        }
      }
#pragma unroll
      for (int b = 0; b < B; ++b) *(float4*)(xcs + b * 1024 + 512 + h4) = acc[b];
    }
    for (int i = tid; i < B * HSZ; i += 512) {
      int b = i >> 9, hcol = i & 511;
      xcs[b * 1024 + hcol] = xs[b * HSZ + hcol];
    }
    __syncthreads();
    int j = blockIdx.x * 8 + wave;  // 0..511
    const float4* w = (const float4*)(Wc + (size_t)j * 1024);
    float4 w0 = w[lane], w1 = w[lane + 64], w2 = w[lane + 128], w3 = w[lane + 192];
#pragma unroll
    for (int b = 0; b < B; ++b) {
      const float4* xb = (const float4*)(xcs + b * 1024);
      float acc = dot4(w0, xb[lane]) + dot4(w1, xb[lane + 64]) +
                  dot4(w2, xb[lane + 128]) + dot4(w3, xb[lane + 192]);
      acc = wsum(acc);
      if (lane == 0) agst(&feat[b * HSZ + j], tanhf(acc));
    }
    __syncthreads();  // drains vmcnt: feat stores at coherence point
    if (tid == 0)
      __hip_atomic_fetch_add(cnt, 1, __ATOMIC_RELAXED, __HIP_MEMORY_SCOPE_AGENT);
  }

  // all blocks: single-thread backoff poll (r12-validated)
  if (tid == 0) {
    int target = ep * 64;
    long it = 0;
    while (agldi(cnt) < target && it < 50000000L) { __builtin_amdgcn_s_sleep(4); ++it; }
  }
  asm volatile("" ::: "memory");
  __syncthreads();

  for (int i = tid; i < B * HSZ; i += 512) fst[i] = agld(&feat[i]);
  __syncthreads();

  // logits: 4 lanes per row; each lane streams a contiguous 512B quarter-row
  int gq   = blockIdx.x * 512 + tid;
  int grow = gq >> 2;        // row
  int qtr  = tid & 3;        // quarter
  float m[B], ss[B], tv[B][3];
  int tix[B][3];
#pragma unroll
  for (int b = 0; b < B; ++b) {
    m[b] = -INFINITY; ss[b] = 0.f;
#pragma unroll
    for (int k = 0; k < 3; ++k) { tv[b][k] = -INFINITY; tix[b][k] = 0x7fffffff; }
  }
  if (grow < VOC) {
    const float4* wr = (const float4*)(Wout + (size_t)grow * HSZ) + qtr * 32;
    const float4* f4[B];
#pragma unroll
    for (int b = 0; b < B; ++b) f4[b] = ((const float4*)(fst + b * HSZ)) + qtr * 32;
    float acc[B];
#pragma unroll
    for (int b = 0; b < B; ++b) acc[b] = 0.f;
#pragma unroll
    for (int e0 = 0; e0 < 32; e0 += 8) {
      float4 wv[8];
#pragma unroll
      for (int u = 0; u < 8; ++u) wv[u] = wr[e0 + u];
#pragma unroll
      for (int u = 0; u < 8; ++u)
#pragma unroll
        for (int b = 0; b < B; ++b) acc[b] += dot4(wv[u], f4[b][e0 + u]);
    }
    float bo = bout[grow];
#pragma unroll
    for (int b = 0; b < B; ++b) {
      float t = acc[b];
      t += __shfl_xor(t, 1, 64);
      t += __shfl_xor(t, 2, 64);
      if (qtr == 0) {
        float logit = t + bo;
        m[b] = logit; ss[b] = 1.f; tv[b][0] = logit; tix[b][0] = grow;
      }
    }
  }
  // wave butterfly merge (guards avoid 0*exp(nan) for neutral lanes)
#pragma unroll
  for (int off = 32; off; off >>= 1) {
#pragma unroll
    for (int b = 0; b < B; ++b) {
      float Mo = __shfl_xor(m[b], off, 64);
      float So = __shfl_xor(ss[b], off, 64);
      float ov[3]; int oi[3];
#pragma unroll
      for (int k = 0; k < 3; ++k) { ov[k] = __shfl_xor(tv[b][k], off, 64); oi[k] = __shfl_xor(tix[b][k], off, 64); }
      float Mn = fmaxf(m[b], Mo);
      float t1 = (ss[b] == 0.f) ? 0.f : ss[b] * expf(m[b] - Mn);
      float t2 = (So == 0.f) ? 0.f : So * expf(Mo - Mn);
      m[b] = Mn; ss[b] = t1 + t2;
#pragma unroll
      for (int k = 0; k < 3; ++k) ins3(tv[b], tix[b], ov[k], oi[k]);
    }
  }
  __shared__ float lm[8][3], lss[8][3], lv[8][3][3];
  __shared__ int li[8][3][3];
  if (lane == 0) {
#pragma unroll
    for (int b = 0; b < B; ++b) {
      lm[wave][b] = m[b]; lss[wave][b] = ss[b];
#pragma unroll
      for (int k = 0; k < 3; ++k) { lv[wave][b][k] = tv[b][k]; li[wave][b][k] = tix[b][k]; }
    }
  }
  __syncthreads();
  if (tid < B) {
    int b = tid;
    float M = -INFINITY;
#pragma unroll
    for (int w2 = 0; w2 < 8; ++w2) M = fmaxf(M, lm[w2][b]);
    float S = 0.f;
#pragma unroll
    for (int w2 = 0; w2 < 8; ++w2)
      S += (lss[w2][b] == 0.f) ? 0.f : lss[w2][b] * expf(lm[w2][b] - M);
    float bv[3] = {-INFINITY, -INFINITY, -INFINITY};
    int bi3[3]  = {0x7fffffff, 0x7fffffff, 0x7fffffff};
#pragma unroll
    for (int w2 = 0; w2 < 8; ++w2)
#pragma unroll
      for (int k = 0; k < 3; ++k) ins3(bv, bi3, lv[w2][b][k], li[w2][b][k]);
    int o = blockIdx.x * 3 + b;
    pm[o] = M; ps[o] = S;
#pragma unroll
    for (int k = 0; k < 3; ++k) { pv[o * 3 + k] = bv[k]; pi[o * 3 + k] = bi3[k]; }
  }
}

// tail: final merge over 256 partials + output write; 1 block x 256 (r11 verbatim)
__global__ void __launch_bounds__(256) k_tail(const float* __restrict__ pm,
                                              const float* __restrict__ ps,
                                              const float* __restrict__ pv,
                                              const int* __restrict__ pi,
                                              const float* __restrict__ scores_rd,
                                              const int* __restrict__ tokens_rd,
                                              int* __restrict__ bt, int* __restrict__ outp) {
  const int ti = TMAX - 2;
  __shared__ float sM[3], sS[3], sV[3][3], sScore[3];
  __shared__ int sI[3][3], sOrig[3], sTokOld[3], sKstar;
  int tid = threadIdx.x, wave = tid >> 6, lane = tid & 63;
  if (wave < 3) {
    int b = wave;
    float lm4[4], ls4[4];
    float M = -INFINITY;
#pragma unroll
    for (int q = 0; q < 4; ++q) {
      int blk2 = lane + q * 64;
      lm4[q] = pm[blk2 * 3 + b]; ls4[q] = ps[blk2 * 3 + b];
      M = fmaxf(M, lm4[q]);
    }
#pragma unroll
    for (int off = 32; off; off >>= 1) M = fmaxf(M, __shfl_xor(M, off, 64));
    float S = 0.f;
#pragma unroll
    for (int q = 0; q < 4; ++q) S += (ls4[q] == 0.f) ? 0.f : ls4[q] * expf(lm4[q] - M);
    S = wsum(S);
    float bv[3] = {-INFINITY, -INFINITY, -INFINITY};
    int bi3[3]  = {0x7fffffff, 0x7fffffff, 0x7fffffff};
#pragma unroll
    for (int q = 0; q < 4; ++q) {
      int blk2 = lane + q * 64;
#pragma unroll
      for (int k = 0; k < 3; ++k)
        ins3(bv, bi3, pv[(blk2 * 3 + b) * 3 + k], pi[(blk2 * 3 + b) * 3 + k]);
    }
#pragma unroll
    for (int off = 32; off; off >>= 1) {
      float ov[3]; int oi[3];
#pragma unroll
      for (int k = 0; k < 3; ++k) { ov[k] = __shfl_xor(bv[k], off, 64); oi[k] = __shfl_xor(bi3[k], off, 64); }
#pragma unroll
      for (int k = 0; k < 3; ++k) ins3(bv, bi3, ov[k], oi[k]);
    }
    if (lane == 0) {
      sM[b] = M; sS[b] = S;
#pragma unroll
      for (int k = 0; k < 3; ++k) { sV[b][k] = bv[k]; sI[b][k] = bi3[k]; }
    }
  }
  __syncthreads();
  if (tid == 0) {
    float osc[3];
    for (int b = 0; b < 3; ++b) { osc[b] = scores_rd[b]; sTokOld[b] = tokens_rd[b]; }
    float cum[9];
    for (int b = 0; b < 3; ++b) {
      float o = osc[b] - sM[b] - logf(sS[b]);
      for (int k = 0; k < 3; ++k) cum[b * 3 + k] = sV[b][k] + o;
    }
    bool used[9] = {false, false, false, false, false, false, false, false, false};
    for (int k = 0; k < 3; ++k) {
      int bf = 0; float bb = -INFINITY;
      for (int f = 0; f < 9; ++f)
        if (!used[f] && cum[f] > bb) { bb = cum[f]; bf = f; }
      used[bf] = true;
      sScore[k] = bb;
      sOrig[k] = bf / 3;
    }
    float bb = -INFINITY; int kk = 0;
    for (int k = 0; k < 3; ++k) if (sScore[k] > bb) { bb = sScore[k]; kk = k; }
    sKstar = kk;
  }
  __syncthreads();
  const int* src = bt + (ti & 1) * (BEAM * TMAX);
  int* dst = bt + ((ti + 1) & 1) * (BEAM * TMAX);
  for (int idx = tid; idx < BEAM * TMAX; idx += 256) {
    int k = idx / TMAX, jj = idx % TMAX, o = sOrig[k];
    dst[idx] = (jj == ti + 1) ? sTokOld[o] : src[o * TMAX + jj];
  }
  __syncthreads();
  for (int jj = tid; jj < TMAX; jj += 256) outp[jj] = dst[sKstar * TMAX + jj];
}

extern "C" void kernel_launch(void* const* d_in, const int* in_sizes, int n_in,
                              void* d_out, int out_size, void* d_ws, size_t ws_size,
                              hipStream_t stream) {
  const int*   seq     = (const int*)d_in[0];
  const float* emb_enc = (const float*)d_in[1];
  const float* Wih_enc = (const float*)d_in[2];
  const float* Whh_enc = (const float*)d_in[3];
  const float* b_enc   = (const float*)d_in[4];
  const float* emb_dec = (const float*)d_in[5];
  const float* Wih_dec = (const float*)d_in[6];
  const float* Whh_dec = (const float*)d_in[7];
  const float* b_dec   = (const float*)d_in[8];
  const float* W_c     = (const float*)d_in[9];
  const float* W_out   = (const float*)d_in[10];
  const float* b_out   = (const float*)d_in[11];
  const int*   bosp    = (const int*)d_in[14];

  int* cnt = (int*)d_ws;                   // one counter line
  float* w = (float*)d_ws + FLS;
  float* xp1     = w; w += SEQ * H4;
  float* h1a     = w; w += (SEQ + 1) * HSZ;
  float* c1a     = w; w += (SEQ + 1) * HSZ;
  float* h2a     = w; w += (SEQ + 1) * HSZ;
  float* c2a     = w; w += (SEQ + 1) * HSZ;
  float* hdn1    = w; w += 2 * BEAM * HSZ;
  float* cdn1    = w; w += 2 * BEAM * HSZ;
  float* hdn2    = w; w += 2 * BEAM * HSZ;
  float* cdn2    = w; w += 2 * BEAM * HSZ;
  float* hd2p    = w; w += BEAM * HSZ;
  float* cd2p    = w; w += BEAM * HSZ;
  float* feat    = w; w += BEAM * HSZ;
  float* pm      = w; w += 256 * 3;
  float* ps      = w; w += 256 * 3;
  float* pv      = w; w += 256 * 3 * 3;
  float* sb      = w; w += 2 * 4;
  int* pi     = (int*)w; w += 256 * 3 * 3;
  int* tb     = (int*)w; w += 2 * 4;
  int* bt     = (int*)w; w += 2 * BEAM * TMAX + 4;
  int* outp   = (int*)d_out;

  hipMemsetAsync(cnt, 0, FLS * sizeof(int), stream);

  k_xw1<<<256, 512, 0, stream>>>(Wih_enc, b_enc, emb_enc, seq, xp1);
  for (int s = 0; s <= SEQ; ++s)
    k_encslot<<<256, 512, 0, stream>>>(Whh_enc, Wih_enc + LOFF, Whh_enc + LOFF, b_enc + H4,
                                       xp1, h1a, c1a, h2a, c2a, s);

  for (int s = 0; s < TMAX; ++s) {
    int rp = (s - 1) & 1, wp = s & 1;
    if (s == 0) {
      k_dcell1<1, 1, 0><<<256, 512, 0, stream>>>(
          Wih_dec, Whh_dec, b_dec, emb_dec, bosp,
          h1a + SEQ * HSZ, c1a + SEQ * HSZ, h2a + SEQ * HSZ, c2a + SEQ * HSZ,
          pm, ps, pv, pi,
          hdn1 + 0, cdn1 + 0, hd2p, cd2p,
          sb, sb, tb, tb, bt, 0);
      k_dcell2<1><<<256, 512, 0, stream>>>(Wih_dec + LOFF, Whh_dec + LOFF, b_dec + H4,
                                           hdn1 + 0, hd2p, cd2p, hdn2 + 0, cdn2 + 0);
      k_atlg2<1><<<256, 512, 0, stream>>>(hdn2 + 0, h2a, W_c, W_out, b_out, feat,
                                          pm, ps, pv, pi, cnt, s + 1);
    } else {
      float* h1p = hdn1 + rp * BEAM * HSZ; float* c1p = cdn1 + rp * BEAM * HSZ;
      float* h2p = hdn2 + rp * BEAM * HSZ; float* c2p = cdn2 + rp * BEAM * HSZ;
      float* h1o = hdn1 + wp * BEAM * HSZ; float* c1o = cdn1 + wp * BEAM * HSZ;
      float* h2o = hdn2 + wp * BEAM * HSZ; float* c2o = cdn2 + wp * BEAM * HSZ;
      if (s == 1)
        k_dcell1<3, 1, 1><<<256, 512, 0, stream>>>(
            Wih_dec, Whh_dec, b_dec, emb_dec, bosp,
            h1p, c1p, h2p, c2p, pm, ps, pv, pi,
            h1o, c1o, hd2p, cd2p,
            sb + rp * 4, sb + wp * 4, tb + rp * 4, tb + wp * 4, bt, -1);
      else
        k_dcell1<3, 3, 2><<<256, 512, 0, stream>>>(
            Wih_dec, Whh_dec, b_dec, emb_dec, bosp,
            h1p, c1p, h2p, c2p, pm, ps, pv, pi,
            h1o, c1o, hd2p, cd2p,
            sb + rp * 4, sb + wp * 4, tb + rp * 4, tb + wp * 4, bt, s - 2);
      k_dcell2<3><<<256, 512, 0, stream>>>(Wih_dec + LOFF, Whh_dec + LOFF, b_dec + H4,
                                           h1o, hd2p, cd2p, h2o, c2o);
      k_atlg2<3><<<256, 512, 0, stream>>>(h2o, h2a, W_c, W_out, b_out, feat,
                                          pm, ps, pv, pi, cnt, s + 1);
    }
  }
  k_tail<<<1, 256, 0, stream>>>(pm, ps, pv, pi, sb + 4, tb + 4, bt, outp);
}

// Round 15
// 3760.656 us; speedup vs baseline: 1.3072x; 1.3072x over previous
//
#include <hip/hip_runtime.h>
#include <math.h>

// Problem constants (fixed by the reference module)
#define HSZ   512
#define H4    2048
#define SEQ   64
#define VOC   32000
#define BEAM  3
#define TMAX  50
#define FLS   16   // flag line stride in ints (64 B)

#define LOFF  ((size_t)H4 * HSZ)   // per-layer weight stride

__device__ __forceinline__ float wsum(float v) {
#pragma unroll
  for (int off = 32; off; off >>= 1) v += __shfl_xor(v, off, 64);
  return v;
}
__device__ __forceinline__ float dot4(float4 a, float4 b) {
  return a.x * b.x + a.y * b.y + a.z * b.z + a.w * b.w;
}
__device__ __forceinline__ float sigf(float x) { return 1.f / (1.f + expf(-x)); }

__device__ __forceinline__ bool better(float v1, int i1, float v2, int i2) {
  return (v1 > v2) || (v1 == v2 && i1 < i2);  // jax.lax.top_k order: value desc, index asc
}
__device__ __forceinline__ void ins3(float* v, int* idx, float nv, int ni) {
  if (better(nv, ni, v[2], idx[2])) {
    if (better(nv, ni, v[1], idx[1])) {
      v[2] = v[1]; idx[2] = idx[1];
      if (better(nv, ni, v[0], idx[0])) { v[1] = v[0]; idx[1] = idx[0]; v[0] = nv; idx[0] = ni; }
      else { v[1] = nv; idx[1] = ni; }
    } else { v[2] = nv; idx[2] = ni; }
  }
}

// coherent accessors (agent scope, relaxed) — validated bit-exact rounds 5-14
__device__ __forceinline__ float agld(const float* p) {
  return __hip_atomic_load(p, __ATOMIC_RELAXED, __HIP_MEMORY_SCOPE_AGENT);
}
__device__ __forceinline__ void agst(float* p, float v) {
  __hip_atomic_store(p, v, __ATOMIC_RELAXED, __HIP_MEMORY_SCOPE_AGENT);
}
__device__ __forceinline__ int agldi(const int* p) {
  return __hip_atomic_load(p, __ATOMIC_RELAXED, __HIP_MEMORY_SCOPE_AGENT);
}

// ---------------- encoder ----------------

__global__ void __launch_bounds__(512) k_xw1(const float* __restrict__ Wih,
                                             const float* __restrict__ bias,
                                             const float* __restrict__ emb,
                                             const int* __restrict__ seq,
                                             float* __restrict__ xp1) {
  int t    = threadIdx.x & 63;
  int wave = threadIdx.x >> 6;
  int r    = blockIdx.x * 8 + wave;
  int tok  = seq[t];
  const float* xr = emb + (size_t)tok * HSZ;
  const float* wr = Wih + (size_t)r * HSZ;
  float acc = 0.f;
  for (int e = 0; e < HSZ; e += 4) {
    float4 wv = *(const float4*)(wr + e);
    float4 xv = *(const float4*)(xr + e);
    acc += dot4(wv, xv);
  }
  xp1[t * H4 + r] = acc + bias[r];
}

__global__ void __launch_bounds__(512) k_encslot(const float* __restrict__ Whh1,
                                                 const float* __restrict__ Wih2,
                                                 const float* __restrict__ Whh2,
                                                 const float* __restrict__ b2,
                                                 const float* __restrict__ xp1,
                                                 float* __restrict__ h1a, float* __restrict__ c1a,
                                                 float* __restrict__ h2a, float* __restrict__ c2a,
                                                 int s) {
  __shared__ float rowX[HSZ], rowH[HSZ], zl[16];
  int tid = threadIdx.x, wave = tid >> 6, lane = tid & 63;
  bool l2 = blockIdx.x >= 128;
  int t = l2 ? s - 1 : s;
  if (t < 0 || t >= SEQ) return;
  int bb = blockIdx.x & 127;
  int lr = wave >> 1;
  int j  = bb * 4 + lr;
  int g0 = (wave & 1) * 2;
  if (!l2) {
    rowX[tid] = (t > 0) ? h1a[t * HSZ + tid] : 0.f;
    __syncthreads();
    float4 h0 = ((const float4*)rowX)[lane], h1v = ((const float4*)rowX)[lane + 64];
#pragma unroll
    for (int gg = 0; gg < 2; ++gg) {
      int g = g0 + gg;
      int row = j + (g << 9);
      const float4* wr = (const float4*)(Whh1 + (size_t)row * HSZ);
      float zs = wsum(dot4(wr[lane], h0) + dot4(wr[lane + 64], h1v));
      if (lane == 0) zl[lr * 4 + g] = zs + xp1[t * H4 + row];
    }
    __syncthreads();
    if (tid < 4) {
      int j2 = bb * 4 + tid;
      float z0 = zl[tid * 4 + 0], z1 = zl[tid * 4 + 1], z2 = zl[tid * 4 + 2], z3 = zl[tid * 4 + 3];
      float cp = (t > 0) ? c1a[t * HSZ + j2] : 0.f;
      float c = sigf(z1) * cp + sigf(z0) * tanhf(z2);
      c1a[(t + 1) * HSZ + j2] = c;
      h1a[(t + 1) * HSZ + j2] = sigf(z3) * tanhf(c);
    }
  } else {
    rowX[tid] = h1a[(t + 1) * HSZ + tid];
    rowH[tid] = (t > 0) ? h2a[t * HSZ + tid] : 0.f;
    __syncthreads();
    float4 x0 = ((const float4*)rowX)[lane], x1 = ((const float4*)rowX)[lane + 64];
    float4 h0 = ((const float4*)rowH)[lane], h1v = ((const float4*)rowH)[lane + 64];
#pragma unroll
    for (int gg = 0; gg < 2; ++gg) {
      int g = g0 + gg;
      int row = j + (g << 9);
      const float4* wi = (const float4*)(Wih2 + (size_t)row * HSZ);
      const float4* wh = (const float4*)(Whh2 + (size_t)row * HSZ);
      float zs = wsum(dot4(wi[lane], x0) + dot4(wi[lane + 64], x1) +
                      dot4(wh[lane], h0) + dot4(wh[lane + 64], h1v));
      if (lane == 0) zl[lr * 4 + g] = zs + b2[row];
    }
    __syncthreads();
    if (tid < 4) {
      int j2 = bb * 4 + tid;
      float z0 = zl[tid * 4 + 0], z1 = zl[tid * 4 + 1], z2 = zl[tid * 4 + 2], z3 = zl[tid * 4 + 3];
      float cp = (t > 0) ? c2a[t * HSZ + j2] : 0.f;
      float c = sigf(z1) * cp + sigf(z0) * tanhf(z2);
      c2a[(t + 1) * HSZ + j2] = c;
      h2a[(t + 1) * HSZ + j2] = sigf(z3) * tanhf(c);
    }
  }
}

// ---------------- decoder ----------------

// Layer-1 cell with FUSED beam merge over 256 partial sets (r14 verbatim, passed).
template <int B, int BIN, int MODE>
__global__ void __launch_bounds__(512) k_dcell1(
    const float* __restrict__ Wih, const float* __restrict__ Whh,
    const float* __restrict__ bias,
    const float* __restrict__ emb_dec, const int* __restrict__ bosp,
    const float* __restrict__ h1prev, const float* __restrict__ c1prev,
    const float* __restrict__ h2prev, const float* __restrict__ c2prev,
    const float* __restrict__ pm, const float* __restrict__ ps,
    const float* __restrict__ pv, const int* __restrict__ pi,
    float* __restrict__ hout, float* __restrict__ cout,
    float* __restrict__ hd2p, float* __restrict__ cd2p,
    const float* __restrict__ scores_rd, float* __restrict__ scores_wr,
    const int* __restrict__ tokens_rd, int* __restrict__ tokens_wr,
    int* __restrict__ bt, int ti) {
  __shared__ float xl[B * HSZ], hl[B * HSZ], cl[B * HSZ], zl[8 * B];
  __shared__ float sM[3], sS[3], sV[3][3], sScore[3];
  __shared__ int sI[3][3], sOrig[3], sTokNew[3], sTokOld[3];
  int tid = threadIdx.x, wave = tid >> 6, lane = tid & 63;

  if (MODE >= 1) {
    if (wave < BIN) {
      int b = wave;
      float lm4[4], ls4[4];
      float M = -INFINITY;
#pragma unroll
      for (int q = 0; q < 4; ++q) {
        int blk2 = lane + q * 64;
        lm4[q] = pm[blk2 * 3 + b]; ls4[q] = ps[blk2 * 3 + b];
        M = fmaxf(M, lm4[q]);
      }
#pragma unroll
      for (int off = 32; off; off >>= 1) M = fmaxf(M, __shfl_xor(M, off, 64));
      float S = 0.f;
#pragma unroll
      for (int q = 0; q < 4; ++q) S += (ls4[q] == 0.f) ? 0.f : ls4[q] * expf(lm4[q] - M);
      S = wsum(S);
      float bv[3] = {-INFINITY, -INFINITY, -INFINITY};
      int bi3[3]  = {0x7fffffff, 0x7fffffff, 0x7fffffff};
#pragma unroll
      for (int q = 0; q < 4; ++q) {
        int blk2 = lane + q * 64;
#pragma unroll
        for (int k = 0; k < 3; ++k)
          ins3(bv, bi3, pv[(blk2 * 3 + b) * 3 + k], pi[(blk2 * 3 + b) * 3 + k]);
      }
#pragma unroll
      for (int off = 32; off; off >>= 1) {
        float ov[3]; int oi[3];
#pragma unroll
        for (int k = 0; k < 3; ++k) { ov[k] = __shfl_xor(bv[k], off, 64); oi[k] = __shfl_xor(bi3[k], off, 64); }
#pragma unroll
        for (int k = 0; k < 3; ++k) ins3(bv, bi3, ov[k], oi[k]);
      }
      if (lane == 0) {
        sM[b] = M; sS[b] = S;
#pragma unroll
        for (int k = 0; k < 3; ++k) { sV[b][k] = bv[k]; sI[b][k] = bi3[k]; }
      }
    }
    __syncthreads();
    if (tid == 0) {
      if (MODE == 1) {
        float off0 = -sM[0] - logf(sS[0]);
        for (int k = 0; k < 3; ++k) {
          sScore[k] = sV[0][k] + off0;
          sTokNew[k] = sI[0][k]; sOrig[k] = 0; sTokOld[k] = 0;
        }
      } else {
        float osc[3];
        for (int b = 0; b < 3; ++b) { osc[b] = scores_rd[b]; sTokOld[b] = tokens_rd[b]; }
        float cum[9];
        for (int b = 0; b < 3; ++b) {
          float o = osc[b] - sM[b] - logf(sS[b]);
          for (int k = 0; k < 3; ++k) cum[b * 3 + k] = sV[b][k] + o;
        }
        bool used[9] = {false, false, false, false, false, false, false, false, false};
        for (int k = 0; k < 3; ++k) {
          int bf = 0; float bb = -INFINITY;
          for (int f = 0; f < 9; ++f)
            if (!used[f] && cum[f] > bb) { bb = cum[f]; bf = f; }  // strict >: lowest flat idx on tie
          used[bf] = true;
          sScore[k] = bb;
          int ob = bf / 3;
          sOrig[k] = ob;
          sTokNew[k] = sI[ob][bf - ob * 3];
        }
      }
    }
    __syncthreads();
  }

  if (MODE == 0) {
    int bos = bosp[0];
    for (int i = tid; i < B * HSZ; i += 512) {
      xl[i] = emb_dec[(size_t)bos * HSZ + i];
      hl[i] = h1prev[i]; cl[i] = c1prev[i];
    }
    if (blockIdx.x == 0) {
      for (int i = tid; i < B * HSZ; i += 512) { hd2p[i] = h2prev[i]; cd2p[i] = c2prev[i]; }
    }
  } else {
    for (int i = tid; i < B * HSZ; i += 512) {
      int b = i >> 9, e = i & 511;
      xl[i] = emb_dec[(size_t)sTokNew[b] * HSZ + e];
      hl[i] = h1prev[sOrig[b] * HSZ + e];
      cl[i] = c1prev[sOrig[b] * HSZ + e];
    }
    if (blockIdx.x == 0) {
      for (int i = tid; i < B * HSZ; i += 512) {
        int b = i >> 9, e = i & 511;
        hd2p[i] = h2prev[sOrig[b] * HSZ + e];
        cd2p[i] = c2prev[sOrig[b] * HSZ + e];
      }
      if (MODE == 1) {
        int bos = bosp[0];
        for (int idx = tid; idx < BEAM * TMAX; idx += 512) bt[idx] = bos;  // buffer 0
      } else {
        const int* src = bt + (ti & 1) * (BEAM * TMAX);
        int* dst = bt + ((ti + 1) & 1) * (BEAM * TMAX);
        for (int idx = tid; idx < BEAM * TMAX; idx += 512) {
          int k = idx / TMAX, jj = idx % TMAX, o = sOrig[k];
          dst[idx] = (jj == ti + 1) ? sTokOld[o] : src[o * TMAX + jj];
        }
      }
      if (tid < 3) { scores_wr[tid] = sScore[tid]; tokens_wr[tid] = sTokNew[tid]; }
    }
  }
  __syncthreads();

  int lr = wave >> 2;
  int g  = wave & 3;
  int j  = blockIdx.x * 2 + lr;
  int row = j + (g << 9);
  const float4* wi = (const float4*)(Wih + (size_t)row * HSZ);
  const float4* wh = (const float4*)(Whh + (size_t)row * HSZ);
  float4 wi0 = wi[lane], wi1 = wi[lane + 64], wh0 = wh[lane], wh1 = wh[lane + 64];
  float bb = bias[row];
#pragma unroll
  for (int b = 0; b < B; ++b) {
    float4 xv0 = ((const float4*)(xl + b * HSZ))[lane];
    float4 xv1 = ((const float4*)(xl + b * HSZ))[lane + 64];
    float4 hv0 = ((const float4*)(hl + b * HSZ))[lane];
    float4 hv1 = ((const float4*)(hl + b * HSZ))[lane + 64];
    float acc = dot4(wi0, xv0) + dot4(wi1, xv1) + dot4(wh0, hv0) + dot4(wh1, hv1);
    float z = wsum(acc) + bb;
    if (lane == 0) zl[(lr * 4 + g) * B + b] = z;
  }
  __syncthreads();
  for (int q = tid; q < 2 * B; q += 512) {
    int lr2 = q / B, b = q % B;
    int j2 = blockIdx.x * 2 + lr2;
    float z0 = zl[(lr2 * 4 + 0) * B + b], z1 = zl[(lr2 * 4 + 1) * B + b];
    float z2 = zl[(lr2 * 4 + 2) * B + b], z3 = zl[(lr2 * 4 + 3) * B + b];
    float c = sigf(z1) * cl[b * HSZ + j2] + sigf(z0) * tanhf(z2);
    cout[b * HSZ + j2] = c;
    hout[b * HSZ + j2] = sigf(z3) * tanhf(c);
  }
}

// layer-2 cell (r14 verbatim)
template <int B>
__global__ void __launch_bounds__(512) k_dcell2(const float* __restrict__ Wih,
                                                const float* __restrict__ Whh,
                                                const float* __restrict__ bias,
                                                const float* __restrict__ x,
                                                const float* __restrict__ hin,
                                                const float* __restrict__ cin,
                                                float* __restrict__ hout, float* __restrict__ cout) {
  __shared__ float xl[B * HSZ], hl[B * HSZ], cl[B * HSZ], zl[8 * B];
  int tid = threadIdx.x;
  for (int i = tid; i < B * HSZ; i += 512) { xl[i] = x[i]; hl[i] = hin[i]; cl[i] = cin[i]; }
  __syncthreads();
  int wave = tid >> 6, lane = tid & 63;
  int lr = wave >> 2;
  int g  = wave & 3;
  int j  = blockIdx.x * 2 + lr;
  int row = j + (g << 9);
  const float4* wi = (const float4*)(Wih + (size_t)row * HSZ);
  const float4* wh = (const float4*)(Whh + (size_t)row * HSZ);
  float4 wi0 = wi[lane], wi1 = wi[lane + 64], wh0 = wh[lane], wh1 = wh[lane + 64];
  float bb = bias[row];
#pragma unroll
  for (int b = 0; b < B; ++b) {
    float4 xv0 = ((const float4*)(xl + b * HSZ))[lane];
    float4 xv1 = ((const float4*)(xl + b * HSZ))[lane + 64];
    float4 hv0 = ((const float4*)(hl + b * HSZ))[lane];
    float4 hv1 = ((const float4*)(hl + b * HSZ))[lane + 64];
    float acc = dot4(wi0, xv0) + dot4(wi1, xv1) + dot4(wh0, hv0) + dot4(wh1, hv1);
    float z = wsum(acc) + bb;
    if (lane == 0) zl[(lr * 4 + g) * B + b] = z;
  }
  __syncthreads();
  for (int q = tid; q < 2 * B; q += 512) {
    int lr2 = q / B, b = q % B;
    int j2 = blockIdx.x * 2 + lr2;
    float z0 = zl[(lr2 * 4 + 0) * B + b], z1 = zl[(lr2 * 4 + 1) * B + b];
    float z2 = zl[(lr2 * 4 + 2) * B + b], z3 = zl[(lr2 * 4 + 3) * B + b];
    float c = sigf(z1) * cl[b * HSZ + j2] + sigf(z0) * tanhf(z2);
    cout[b * HSZ + j2] = c;
    hout[b * HSZ + j2] = sigf(z3) * tanhf(c);
  }
}

// FUSED attfeat (blocks 0..63) -> counter sync -> LDS-tiled logits sweep.
// Blocks 0..249 own 128 contiguous rows each (250*128 = 32000 exact);
// blocks 250..255 emit neutral partials (zero-guard merge validated r14).
template <int B>
__global__ void __launch_bounds__(512) k_atlg3(const float* __restrict__ h2,
                                               const float* __restrict__ enc,
                                               const float* __restrict__ Wc,
                                               const float* __restrict__ Wout,
                                               const float* __restrict__ bout,
                                               float* __restrict__ feat,
                                               float* __restrict__ pm, float* __restrict__ ps,
                                               float* __restrict__ pv, int* __restrict__ pi,
                                               int* __restrict__ cnt, int ep) {
  __shared__ float xs[BEAM * HSZ], at[BEAM * SEQ], xcs[BEAM * 1024];
  __shared__ float fst[BEAM * HSZ];
  __shared__ float tile[16 * HSZ];   // 32 KB staging tile
  int tid = threadIdx.x, wave = tid >> 6, lane = tid & 63;

  if (blockIdx.x < 64) {  // producer: attention + context + feat (verbatim r11-r14)
    for (int i = tid; i < B * HSZ; i += 512) xs[i] = h2[i];
    __syncthreads();
    if (tid < B * SEQ) {
      int b = tid >> 6, s2 = tid & 63;
      const float* er = enc + (s2 + 1) * HSZ;
      const float* xb = xs + b * HSZ;
      float acc = 0.f;
      for (int e = 0; e < HSZ; e += 4) {
        float4 ev = *(const float4*)(er + e);
        acc += ev.x * xb[e] + ev.y * xb[e + 1] + ev.z * xb[e + 2] + ev.w * xb[e + 3];
      }
      at[tid] = acc;
    }
    __syncthreads();
    if (tid < B) {
      float m = -INFINITY;
      for (int s2 = 0; s2 < SEQ; ++s2) m = fmaxf(m, at[tid * SEQ + s2]);
      float s = 0.f;
      for (int s2 = 0; s2 < SEQ; ++s2) { float e = expf(at[tid * SEQ + s2] - m); at[tid * SEQ + s2] = e; s += e; }
      float inv = 1.f / s;
      for (int s2 = 0; s2 < SEQ; ++s2) at[tid * SEQ + s2] *= inv;
    }
    __syncthreads();
    if (tid < 128) {
      int h4 = tid * 4;
      float4 acc[B];
#pragma unroll
      for (int b = 0; b < B; ++b) acc[b] = make_float4(0.f, 0.f, 0.f, 0.f);
      for (int s2 = 0; s2 < SEQ; ++s2) {
        float4 ev = *(const float4*)(enc + (s2 + 1) * HSZ + h4);
#pragma unroll
        for (int b = 0; b < B; ++b) {
          float a = at[b * SEQ + s2];
          acc[b].x += a * ev.x; acc[b].y += a * ev.y; acc[b].z += a * ev.z; acc[b].w += a * ev.w;
        }
      }
#pragma unroll
      for (int b = 0; b < B; ++b) *(float4*)(xcs + b * 1024 + 512 + h4) = acc[b];
    }
    for (int i = tid; i < B * HSZ; i += 512) {
      int b = i >> 9, hcol = i & 511;
      xcs[b * 1024 + hcol] = xs[b * HSZ + hcol];
    }
    __syncthreads();
    int j = blockIdx.x * 8 + wave;  // 0..511
    const float4* w = (const float4*)(Wc + (size_t)j * 1024);
    float4 w0 = w[lane], w1 = w[lane + 64], w2 = w[lane + 128], w3 = w[lane + 192];
#pragma unroll
    for (int b = 0; b < B; ++b) {
      const float4* xb = (const float4*)(xcs + b * 1024);
      float acc = dot4(w0, xb[lane]) + dot4(w1, xb[lane + 64]) +
                  dot4(w2, xb[lane + 128]) + dot4(w3, xb[lane + 192]);
      acc = wsum(acc);
      if (lane == 0) agst(&feat[b * HSZ + j], tanhf(acc));
    }
    __syncthreads();  // drains vmcnt: feat stores at coherence point
    if (tid == 0)
      __hip_atomic_fetch_add(cnt, 1, __ATOMIC_RELAXED, __HIP_MEMORY_SCOPE_AGENT);
  }

  // all blocks: single-thread backoff poll (r12/r14-validated)
  if (tid == 0) {
    int target = ep * 64;
    long it = 0;
    while (agldi(cnt) < target && it < 50000000L) { __builtin_amdgcn_s_sleep(4); ++it; }
  }
  asm volatile("" ::: "memory");
  __syncthreads();

  for (int i = tid; i < B * HSZ; i += 512) fst[i] = agld(&feat[i]);
  __syncthreads();

  // per-beam feat fragments (r10 lane partition -> per-logit values bit-identical)
  float4 f0[B], f1[B];
#pragma unroll
  for (int b = 0; b < B; ++b) {
    f0[b] = ((const float4*)(fst + b * HSZ))[lane];
    f1[b] = ((const float4*)(fst + b * HSZ))[lane + 64];
  }
  float m[B], ss[B], tv[B][3];
  int tix[B][3];
#pragma unroll
  for (int b = 0; b < B; ++b) {
    m[b] = -INFINITY; ss[b] = 0.f;
#pragma unroll
    for (int k = 0; k < 3; ++k) { tv[b][k] = -INFINITY; tix[b][k] = 0x7fffffff; }
  }

  if (blockIdx.x < 250) {   // block-uniform branch
    int row0 = blockIdx.x * 128;
#pragma unroll 1
    for (int t = 0; t < 8; ++t) {
      // stage 16 rows (32 KB): 512 threads x 4 coalesced float4 loads
      const float4* gsrc = (const float4*)(Wout + (size_t)(row0 + t * 16) * HSZ);
      float4 stg0 = gsrc[0 * 512 + tid];
      float4 stg1 = gsrc[1 * 512 + tid];
      float4 stg2 = gsrc[2 * 512 + tid];
      float4 stg3 = gsrc[3 * 512 + tid];
      __syncthreads();  // previous tile fully consumed
      ((float4*)tile)[0 * 512 + tid] = stg0;
      ((float4*)tile)[1 * 512 + tid] = stg1;
      ((float4*)tile)[2 * 512 + tid] = stg2;
      ((float4*)tile)[3 * 512 + tid] = stg3;
      __syncthreads();  // tile visible to all waves
      // each wave reduces 2 rows (rows ascending within wave across tiles)
#pragma unroll
      for (int rr = 0; rr < 2; ++rr) {
        int rl  = wave * 2 + rr;          // 0..15
        int row = row0 + t * 16 + rl;
        const float4* wr = (const float4*)(tile + rl * HSZ);
        float4 w0 = wr[lane], w1 = wr[lane + 64];
        float bo = bout[row];
#pragma unroll
        for (int b = 0; b < B; ++b) {
          float acc = wsum(dot4(w0, f0[b]) + dot4(w1, f1[b])) + bo;
          float mo = m[b], mn = fmaxf(mo, acc);
          ss[b] = (ss[b] == 0.f) ? expf(acc - mn) : ss[b] * expf(mo - mn) + expf(acc - mn);
          m[b]  = mn;
          ins3(tv[b], tix[b], acc, row);
        }
      }
    }
  }

  __shared__ float lm[8][3], lss[8][3], lv[8][3][3];
  __shared__ int li[8][3][3];
  if (lane == 0) {
#pragma unroll
    for (int b = 0; b < B; ++b) {
      lm[wave][b] = m[b]; lss[wave][b] = ss[b];
#pragma unroll
      for (int k = 0; k < 3; ++k) { lv[wave][b][k] = tv[b][k]; li[wave][b][k] = tix[b][k]; }
    }
  }
  __syncthreads();
  if (tid < B) {
    int b = tid;
    float M = -INFINITY;
#pragma unroll
    for (int w2 = 0; w2 < 8; ++w2) M = fmaxf(M, lm[w2][b]);
    float S = 0.f;
#pragma unroll
    for (int w2 = 0; w2 < 8; ++w2)
      S += (lss[w2][b] == 0.f) ? 0.f : lss[w2][b] * expf(lm[w2][b] - M);
    float bv[3] = {-INFINITY, -INFINITY, -INFINITY};
    int bi3[3]  = {0x7fffffff, 0x7fffffff, 0x7fffffff};
#pragma unroll
    for (int w2 = 0; w2 < 8; ++w2)
#pragma unroll
      for (int k = 0; k < 3; ++k) ins3(bv, bi3, lv[w2][b][k], li[w2][b][k]);
    int o = blockIdx.x * 3 + b;
    pm[o] = M; ps[o] = S;
#pragma unroll
    for (int k = 0; k < 3; ++k) { pv[o * 3 + k] = bv[k]; pi[o * 3 + k] = bi3[k]; }
  }
}

// tail: final merge over 256 partials + output write; 1 block x 256 (r14 verbatim)
__global__ void __launch_bounds__(256) k_tail(const float* __restrict__ pm,
                                              const float* __restrict__ ps,
                                              const float* __restrict__ pv,
                                              const int* __restrict__ pi,
                                              const float* __restrict__ scores_rd,
                                              const int* __restrict__ tokens_rd,
                                              int* __restrict__ bt, int* __restrict__ outp) {
  const int ti = TMAX - 2;
  __shared__ float sM[3], sS[3], sV[3][3], sScore[3];
  __shared__ int sI[3][3], sOrig[3], sTokOld[3], sKstar;
  int tid = threadIdx.x, wave = tid >> 6, lane = tid & 63;
  if (wave < 3) {
    int b = wave;
    float lm4[4], ls4[4];
    float M = -INFINITY;
#pragma unroll
    for (int q = 0; q < 4; ++q) {
      int blk2 = lane + q * 64;
      lm4[q] = pm[blk2 * 3 + b]; ls4[q] = ps[blk2 * 3 + b];
      M = fmaxf(M, lm4[q]);
    }
#pragma unroll
    for (int off = 32; off; off >>= 1) M = fmaxf(M, __shfl_xor(M, off, 64));
    float S = 0.f;
#pragma unroll
    for (int q = 0; q < 4; ++q) S += (ls4[q] == 0.f) ? 0.f : ls4[q] * expf(lm4[q] - M);
    S = wsum(S);
    float bv[3] = {-INFINITY, -INFINITY, -INFINITY};
    int bi3[3]  = {0x7fffffff, 0x7fffffff, 0x7fffffff};
#pragma unroll
    for (int q = 0; q < 4; ++q) {
      int blk2 = lane + q * 64;
#pragma unroll
      for (int k = 0; k < 3; ++k)
        ins3(bv, bi3, pv[(blk2 * 3 + b) * 3 + k], pi[(blk2 * 3 + b) * 3 + k]);
    }
#pragma unroll
    for (int off = 32; off; off >>= 1) {
      float ov[3]; int oi[3];
#pragma unroll
      for (int k = 0; k < 3; ++k) { ov[k] = __shfl_xor(bv[k], off, 64); oi[k] = __shfl_xor(bi3[k], off, 64); }
#pragma unroll
      for (int k = 0; k < 3; ++k) ins3(bv, bi3, ov[k], oi[k]);
    }
    if (lane == 0) {
      sM[b] = M; sS[b] = S;
#pragma unroll
      for (int k = 0; k < 3; ++k) { sV[b][k] = bv[k]; sI[b][k] = bi3[k]; }
    }
  }
  __syncthreads();
  if (tid == 0) {
    float osc[3];
    for (int b = 0; b < 3; ++b) { osc[b] = scores_rd[b]; sTokOld[b] = tokens_rd[b]; }
    float cum[9];
    for (int b = 0; b < 3; ++b) {
      float o = osc[b] - sM[b] - logf(sS[b]);
      for (int k = 0; k < 3; ++k) cum[b * 3 + k] = sV[b][k] + o;
    }
    bool used[9] = {false, false, false, false, false, false, false, false, false};
    for (int k = 0; k < 3; ++k) {
      int bf = 0; float bb = -INFINITY;
      for (int f = 0; f < 9; ++f)
        if (!used[f] && cum[f] > bb) { bb = cum[f]; bf = f; }
      used[bf] = true;
      sScore[k] = bb;
      sOrig[k] = bf / 3;
    }
    float bb = -INFINITY; int kk = 0;
    for (int k = 0; k < 3; ++k) if (sScore[k] > bb) { bb = sScore[k]; kk = k; }
    sKstar = kk;
  }
  __syncthreads();
  const int* src = bt + (ti & 1) * (BEAM * TMAX);
  int* dst = bt + ((ti + 1) & 1) * (BEAM * TMAX);
  for (int idx = tid; idx < BEAM * TMAX; idx += 256) {
    int k = idx / TMAX, jj = idx % TMAX, o = sOrig[k];
    dst[idx] = (jj == ti + 1) ? sTokOld[o] : src[o * TMAX + jj];
  }
  __syncthreads();
  for (int jj = tid; jj < TMAX; jj += 256) outp[jj] = dst[sKstar * TMAX + jj];
}

extern "C" void kernel_launch(void* const* d_in, const int* in_sizes, int n_in,
                              void* d_out, int out_size, void* d_ws, size_t ws_size,
                              hipStream_t stream) {
  const int*   seq     = (const int*)d_in[0];
  const float* emb_enc = (const float*)d_in[1];
  const float* Wih_enc = (const float*)d_in[2];
  const float* Whh_enc = (const float*)d_in[3];
  const float* b_enc   = (const float*)d_in[4];
  const float* emb_dec = (const float*)d_in[5];
  const float* Wih_dec = (const float*)d_in[6];
  const float* Whh_dec = (const float*)d_in[7];
  const float* b_dec   = (const float*)d_in[8];
  const float* W_c     = (const float*)d_in[9];
  const float* W_out   = (const float*)d_in[10];
  const float* b_out   = (const float*)d_in[11];
  const int*   bosp    = (const int*)d_in[14];

  int* cnt = (int*)d_ws;                   // one counter line
  float* w = (float*)d_ws + FLS;
  float* xp1     = w; w += SEQ * H4;
  float* h1a     = w; w += (SEQ + 1) * HSZ;
  float* c1a     = w; w += (SEQ + 1) * HSZ;
  float* h2a     = w; w += (SEQ + 1) * HSZ;
  float* c2a     = w; w += (SEQ + 1) * HSZ;
  float* hdn1    = w; w += 2 * BEAM * HSZ;
  float* cdn1    = w; w += 2 * BEAM * HSZ;
  float* hdn2    = w; w += 2 * BEAM * HSZ;
  float* cdn2    = w; w += 2 * BEAM * HSZ;
  float* hd2p    = w; w += BEAM * HSZ;
  float* cd2p    = w; w += BEAM * HSZ;
  float* feat    = w; w += BEAM * HSZ;
  float* pm      = w; w += 256 * 3;
  float* ps      = w; w += 256 * 3;
  float* pv      = w; w += 256 * 3 * 3;
  float* sb      = w; w += 2 * 4;
  int* pi     = (int*)w; w += 256 * 3 * 3;
  int* tb     = (int*)w; w += 2 * 4;
  int* bt     = (int*)w; w += 2 * BEAM * TMAX + 4;
  int* outp   = (int*)d_out;

  hipMemsetAsync(cnt, 0, FLS * sizeof(int), stream);

  k_xw1<<<256, 512, 0, stream>>>(Wih_enc, b_enc, emb_enc, seq, xp1);
  for (int s = 0; s <= SEQ; ++s)
    k_encslot<<<256, 512, 0, stream>>>(Whh_enc, Wih_enc + LOFF, Whh_enc + LOFF, b_enc + H4,
                                       xp1, h1a, c1a, h2a, c2a, s);

  for (int s = 0; s < TMAX; ++s) {
    int rp = (s - 1) & 1, wp = s & 1;
    if (s == 0) {
      k_dcell1<1, 1, 0><<<256, 512, 0, stream>>>(
          Wih_dec, Whh_dec, b_dec, emb_dec, bosp,
          h1a + SEQ * HSZ, c1a + SEQ * HSZ, h2a + SEQ * HSZ, c2a + SEQ * HSZ,
          pm, ps, pv, pi,
          hdn1 + 0, cdn1 + 0, hd2p, cd2p,
          sb, sb, tb, tb, bt, 0);
      k_dcell2<1><<<256, 512, 0, stream>>>(Wih_dec + LOFF, Whh_dec + LOFF, b_dec + H4,
                                           hdn1 + 0, hd2p, cd2p, hdn2 + 0, cdn2 + 0);
      k_atlg3<1><<<256, 512, 0, stream>>>(hdn2 + 0, h2a, W_c, W_out, b_out, feat,
                                          pm, ps, pv, pi, cnt, s + 1);
    } else {
      float* h1p = hdn1 + rp * BEAM * HSZ; float* c1p = cdn1 + rp * BEAM * HSZ;
      float* h2p = hdn2 + rp * BEAM * HSZ; float* c2p = cdn2 + rp * BEAM * HSZ;
      float* h1o = hdn1 + wp * BEAM * HSZ; float* c1o = cdn1 + wp * BEAM * HSZ;
      float* h2o = hdn2 + wp * BEAM * HSZ; float* c2o = cdn2 + wp * BEAM * HSZ;
      if (s == 1)
        k_dcell1<3, 1, 1><<<256, 512, 0, stream>>>(
            Wih_dec, Whh_dec, b_dec, emb_dec, bosp,
            h1p, c1p, h2p, c2p, pm, ps, pv, pi,
            h1o, c1o, hd2p, cd2p,
            sb + rp * 4, sb + wp * 4, tb + rp * 4, tb + wp * 4, bt, -1);
      else
        k_dcell1<3, 3, 2><<<256, 512, 0, stream>>>(
            Wih_dec, Whh_dec, b_dec, emb_dec, bosp,
            h1p, c1p, h2p, c2p, pm, ps, pv, pi,
            h1o, c1o, hd2p, cd2p,
            sb + rp * 4, sb + wp * 4, tb + rp * 4, tb + wp * 4, bt, s - 2);
      k_dcell2<3><<<256, 512, 0, stream>>>(Wih_dec + LOFF, Whh_dec + LOFF, b_dec + H4,
                                           h1o, hd2p, cd2p, h2o, c2o);
      k_atlg3<3><<<256, 512, 0, stream>>>(h2o, h2a, W_c, W_out, b_out, feat,
                                          pm, ps, pv, pi, cnt, s + 1);
    }
  }
  k_tail<<<1, 256, 0, stream>>>(pm, ps, pv, pi, sb + 4, tb + 4, bt, outp);
}

// Round 16
// 3735.707 us; speedup vs baseline: 1.3159x; 1.0067x over previous
//
#include <hip/hip_runtime.h>
#include <math.h>

// Problem constants (fixed by the reference module)
#define HSZ   512
#define H4    2048
#define SEQ   64
#define VOC   32000
#define BEAM  3
#define TMAX  50
#define FLS   16   // flag line stride in ints (64 B)

#define LOFF  ((size_t)H4 * HSZ)   // per-layer weight stride

__device__ __forceinline__ float wsum(float v) {
#pragma unroll
  for (int off = 32; off; off >>= 1) v += __shfl_xor(v, off, 64);
  return v;
}
__device__ __forceinline__ float dot4(float4 a, float4 b) {
  return a.x * b.x + a.y * b.y + a.z * b.z + a.w * b.w;
}
__device__ __forceinline__ float sigf(float x) { return 1.f / (1.f + expf(-x)); }

__device__ __forceinline__ bool better(float v1, int i1, float v2, int i2) {
  return (v1 > v2) || (v1 == v2 && i1 < i2);  // jax.lax.top_k order: value desc, index asc
}
__device__ __forceinline__ void ins3(float* v, int* idx, float nv, int ni) {
  if (better(nv, ni, v[2], idx[2])) {
    if (better(nv, ni, v[1], idx[1])) {
      v[2] = v[1]; idx[2] = idx[1];
      if (better(nv, ni, v[0], idx[0])) { v[1] = v[0]; idx[1] = idx[0]; v[0] = nv; idx[0] = ni; }
      else { v[1] = nv; idx[1] = ni; }
    } else { v[2] = nv; idx[2] = ni; }
  }
}

// coherent accessors (agent scope, relaxed) — validated bit-exact rounds 5-15
__device__ __forceinline__ float agld(const float* p) {
  return __hip_atomic_load(p, __ATOMIC_RELAXED, __HIP_MEMORY_SCOPE_AGENT);
}
__device__ __forceinline__ void agst(float* p, float v) {
  __hip_atomic_store(p, v, __ATOMIC_RELAXED, __HIP_MEMORY_SCOPE_AGENT);
}
__device__ __forceinline__ int agldi(const int* p) {
  return __hip_atomic_load(p, __ATOMIC_RELAXED, __HIP_MEMORY_SCOPE_AGENT);
}

// ---------------- encoder ----------------

__global__ void __launch_bounds__(512) k_xw1(const float* __restrict__ Wih,
                                             const float* __restrict__ bias,
                                             const float* __restrict__ emb,
                                             const int* __restrict__ seq,
                                             float* __restrict__ xp1) {
  int t    = threadIdx.x & 63;
  int wave = threadIdx.x >> 6;
  int r    = blockIdx.x * 8 + wave;
  int tok  = seq[t];
  const float* xr = emb + (size_t)tok * HSZ;
  const float* wr = Wih + (size_t)r * HSZ;
  float acc = 0.f;
  for (int e = 0; e < HSZ; e += 4) {
    float4 wv = *(const float4*)(wr + e);
    float4 xv = *(const float4*)(xr + e);
    acc += dot4(wv, xv);
  }
  xp1[t * H4 + r] = acc + bias[r];
}

__global__ void __launch_bounds__(512) k_encslot(const float* __restrict__ Whh1,
                                                 const float* __restrict__ Wih2,
                                                 const float* __restrict__ Whh2,
                                                 const float* __restrict__ b2,
                                                 const float* __restrict__ xp1,
                                                 float* __restrict__ h1a, float* __restrict__ c1a,
                                                 float* __restrict__ h2a, float* __restrict__ c2a,
                                                 int s) {
  __shared__ float rowX[HSZ], rowH[HSZ], zl[16];
  int tid = threadIdx.x, wave = tid >> 6, lane = tid & 63;
  bool l2 = blockIdx.x >= 128;
  int t = l2 ? s - 1 : s;
  if (t < 0 || t >= SEQ) return;
  int bb = blockIdx.x & 127;
  int lr = wave >> 1;
  int j  = bb * 4 + lr;
  int g0 = (wave & 1) * 2;
  if (!l2) {
    rowX[tid] = (t > 0) ? h1a[t * HSZ + tid] : 0.f;
    __syncthreads();
    float4 h0 = ((const float4*)rowX)[lane], h1v = ((const float4*)rowX)[lane + 64];
#pragma unroll
    for (int gg = 0; gg < 2; ++gg) {
      int g = g0 + gg;
      int row = j + (g << 9);
      const float4* wr = (const float4*)(Whh1 + (size_t)row * HSZ);
      float zs = wsum(dot4(wr[lane], h0) + dot4(wr[lane + 64], h1v));
      if (lane == 0) zl[lr * 4 + g] = zs + xp1[t * H4 + row];
    }
    __syncthreads();
    if (tid < 4) {
      int j2 = bb * 4 + tid;
      float z0 = zl[tid * 4 + 0], z1 = zl[tid * 4 + 1], z2 = zl[tid * 4 + 2], z3 = zl[tid * 4 + 3];
      float cp = (t > 0) ? c1a[t * HSZ + j2] : 0.f;
      float c = sigf(z1) * cp + sigf(z0) * tanhf(z2);
      c1a[(t + 1) * HSZ + j2] = c;
      h1a[(t + 1) * HSZ + j2] = sigf(z3) * tanhf(c);
    }
  } else {
    rowX[tid] = h1a[(t + 1) * HSZ + tid];
    rowH[tid] = (t > 0) ? h2a[t * HSZ + tid] : 0.f;
    __syncthreads();
    float4 x0 = ((const float4*)rowX)[lane], x1 = ((const float4*)rowX)[lane + 64];
    float4 h0 = ((const float4*)rowH)[lane], h1v = ((const float4*)rowH)[lane + 64];
#pragma unroll
    for (int gg = 0; gg < 2; ++gg) {
      int g = g0 + gg;
      int row = j + (g << 9);
      const float4* wi = (const float4*)(Wih2 + (size_t)row * HSZ);
      const float4* wh = (const float4*)(Whh2 + (size_t)row * HSZ);
      float zs = wsum(dot4(wi[lane], x0) + dot4(wi[lane + 64], x1) +
                      dot4(wh[lane], h0) + dot4(wh[lane + 64], h1v));
      if (lane == 0) zl[lr * 4 + g] = zs + b2[row];
    }
    __syncthreads();
    if (tid < 4) {
      int j2 = bb * 4 + tid;
      float z0 = zl[tid * 4 + 0], z1 = zl[tid * 4 + 1], z2 = zl[tid * 4 + 2], z3 = zl[tid * 4 + 3];
      float cp = (t > 0) ? c2a[t * HSZ + j2] : 0.f;
      float c = sigf(z1) * cp + sigf(z0) * tanhf(z2);
      c2a[(t + 1) * HSZ + j2] = c;
      h2a[(t + 1) * HSZ + j2] = sigf(z3) * tanhf(c);
    }
  }
}

// ---------------- decoder ----------------

// Layer-1 cell with FUSED beam merge over 256 partial sets (r14/r15 verbatim, passed).
template <int B, int BIN, int MODE>
__global__ void __launch_bounds__(512) k_dcell1(
    const float* __restrict__ Wih, const float* __restrict__ Whh,
    const float* __restrict__ bias,
    const float* __restrict__ emb_dec, const int* __restrict__ bosp,
    const float* __restrict__ h1prev, const float* __restrict__ c1prev,
    const float* __restrict__ h2prev, const float* __restrict__ c2prev,
    const float* __restrict__ pm, const float* __restrict__ ps,
    const float* __restrict__ pv, const int* __restrict__ pi,
    float* __restrict__ hout, float* __restrict__ cout,
    float* __restrict__ hd2p, float* __restrict__ cd2p,
    const float* __restrict__ scores_rd, float* __restrict__ scores_wr,
    const int* __restrict__ tokens_rd, int* __restrict__ tokens_wr,
    int* __restrict__ bt, int ti) {
  __shared__ float xl[B * HSZ], hl[B * HSZ], cl[B * HSZ], zl[8 * B];
  __shared__ float sM[3], sS[3], sV[3][3], sScore[3];
  __shared__ int sI[3][3], sOrig[3], sTokNew[3], sTokOld[3];
  int tid = threadIdx.x, wave = tid >> 6, lane = tid & 63;

  if (MODE >= 1) {
    if (wave < BIN) {
      int b = wave;
      float lm4[4], ls4[4];
      float M = -INFINITY;
#pragma unroll
      for (int q = 0; q < 4; ++q) {
        int blk2 = lane + q * 64;
        lm4[q] = pm[blk2 * 3 + b]; ls4[q] = ps[blk2 * 3 + b];
        M = fmaxf(M, lm4[q]);
      }
#pragma unroll
      for (int off = 32; off; off >>= 1) M = fmaxf(M, __shfl_xor(M, off, 64));
      float S = 0.f;
#pragma unroll
      for (int q = 0; q < 4; ++q) S += (ls4[q] == 0.f) ? 0.f : ls4[q] * expf(lm4[q] - M);
      S = wsum(S);
      float bv[3] = {-INFINITY, -INFINITY, -INFINITY};
      int bi3[3]  = {0x7fffffff, 0x7fffffff, 0x7fffffff};
#pragma unroll
      for (int q = 0; q < 4; ++q) {
        int blk2 = lane + q * 64;
#pragma unroll
        for (int k = 0; k < 3; ++k)
          ins3(bv, bi3, pv[(blk2 * 3 + b) * 3 + k], pi[(blk2 * 3 + b) * 3 + k]);
      }
#pragma unroll
      for (int off = 32; off; off >>= 1) {
        float ov[3]; int oi[3];
#pragma unroll
        for (int k = 0; k < 3; ++k) { ov[k] = __shfl_xor(bv[k], off, 64); oi[k] = __shfl_xor(bi3[k], off, 64); }
#pragma unroll
        for (int k = 0; k < 3; ++k) ins3(bv, bi3, ov[k], oi[k]);
      }
      if (lane == 0) {
        sM[b] = M; sS[b] = S;
#pragma unroll
        for (int k = 0; k < 3; ++k) { sV[b][k] = bv[k]; sI[b][k] = bi3[k]; }
      }
    }
    __syncthreads();
    if (tid == 0) {
      if (MODE == 1) {
        float off0 = -sM[0] - logf(sS[0]);
        for (int k = 0; k < 3; ++k) {
          sScore[k] = sV[0][k] + off0;
          sTokNew[k] = sI[0][k]; sOrig[k] = 0; sTokOld[k] = 0;
        }
      } else {
        float osc[3];
        for (int b = 0; b < 3; ++b) { osc[b] = scores_rd[b]; sTokOld[b] = tokens_rd[b]; }
        float cum[9];
        for (int b = 0; b < 3; ++b) {
          float o = osc[b] - sM[b] - logf(sS[b]);
          for (int k = 0; k < 3; ++k) cum[b * 3 + k] = sV[b][k] + o;
        }
        bool used[9] = {false, false, false, false, false, false, false, false, false};
        for (int k = 0; k < 3; ++k) {
          int bf = 0; float bb = -INFINITY;
          for (int f = 0; f < 9; ++f)
            if (!used[f] && cum[f] > bb) { bb = cum[f]; bf = f; }  // strict >: lowest flat idx on tie
          used[bf] = true;
          sScore[k] = bb;
          int ob = bf / 3;
          sOrig[k] = ob;
          sTokNew[k] = sI[ob][bf - ob * 3];
        }
      }
    }
    __syncthreads();
  }

  if (MODE == 0) {
    int bos = bosp[0];
    for (int i = tid; i < B * HSZ; i += 512) {
      xl[i] = emb_dec[(size_t)bos * HSZ + i];
      hl[i] = h1prev[i]; cl[i] = c1prev[i];
    }
    if (blockIdx.x == 0) {
      for (int i = tid; i < B * HSZ; i += 512) { hd2p[i] = h2prev[i]; cd2p[i] = c2prev[i]; }
    }
  } else {
    for (int i = tid; i < B * HSZ; i += 512) {
      int b = i >> 9, e = i & 511;
      xl[i] = emb_dec[(size_t)sTokNew[b] * HSZ + e];
      hl[i] = h1prev[sOrig[b] * HSZ + e];
      cl[i] = c1prev[sOrig[b] * HSZ + e];
    }
    if (blockIdx.x == 0) {
      for (int i = tid; i < B * HSZ; i += 512) {
        int b = i >> 9, e = i & 511;
        hd2p[i] = h2prev[sOrig[b] * HSZ + e];
        cd2p[i] = c2prev[sOrig[b] * HSZ + e];
      }
      if (MODE == 1) {
        int bos = bosp[0];
        for (int idx = tid; idx < BEAM * TMAX; idx += 512) bt[idx] = bos;  // buffer 0
      } else {
        const int* src = bt + (ti & 1) * (BEAM * TMAX);
        int* dst = bt + ((ti + 1) & 1) * (BEAM * TMAX);
        for (int idx = tid; idx < BEAM * TMAX; idx += 512) {
          int k = idx / TMAX, jj = idx % TMAX, o = sOrig[k];
          dst[idx] = (jj == ti + 1) ? sTokOld[o] : src[o * TMAX + jj];
        }
      }
      if (tid < 3) { scores_wr[tid] = sScore[tid]; tokens_wr[tid] = sTokNew[tid]; }
    }
  }
  __syncthreads();

  int lr = wave >> 2;
  int g  = wave & 3;
  int j  = blockIdx.x * 2 + lr;
  int row = j + (g << 9);
  const float4* wi = (const float4*)(Wih + (size_t)row * HSZ);
  const float4* wh = (const float4*)(Whh + (size_t)row * HSZ);
  float4 wi0 = wi[lane], wi1 = wi[lane + 64], wh0 = wh[lane], wh1 = wh[lane + 64];
  float bb = bias[row];
#pragma unroll
  for (int b = 0; b < B; ++b) {
    float4 xv0 = ((const float4*)(xl + b * HSZ))[lane];
    float4 xv1 = ((const float4*)(xl + b * HSZ))[lane + 64];
    float4 hv0 = ((const float4*)(hl + b * HSZ))[lane];
    float4 hv1 = ((const float4*)(hl + b * HSZ))[lane + 64];
    float acc = dot4(wi0, xv0) + dot4(wi1, xv1) + dot4(wh0, hv0) + dot4(wh1, hv1);
    float z = wsum(acc) + bb;
    if (lane == 0) zl[(lr * 4 + g) * B + b] = z;
  }
  __syncthreads();
  for (int q = tid; q < 2 * B; q += 512) {
    int lr2 = q / B, b = q % B;
    int j2 = blockIdx.x * 2 + lr2;
    float z0 = zl[(lr2 * 4 + 0) * B + b], z1 = zl[(lr2 * 4 + 1) * B + b];
    float z2 = zl[(lr2 * 4 + 2) * B + b], z3 = zl[(lr2 * 4 + 3) * B + b];
    float c = sigf(z1) * cl[b * HSZ + j2] + sigf(z0) * tanhf(z2);
    cout[b * HSZ + j2] = c;
    hout[b * HSZ + j2] = sigf(z3) * tanhf(c);
  }
}

// layer-2 cell (r14/r15 verbatim)
template <int B>
__global__ void __launch_bounds__(512) k_dcell2(const float* __restrict__ Wih,
                                                const float* __restrict__ Whh,
                                                const float* __restrict__ bias,
                                                const float* __restrict__ x,
                                                const float* __restrict__ hin,
                                                const float* __restrict__ cin,
                                                float* __restrict__ hout, float* __restrict__ cout) {
  __shared__ float xl[B * HSZ], hl[B * HSZ], cl[B * HSZ], zl[8 * B];
  int tid = threadIdx.x;
  for (int i = tid; i < B * HSZ; i += 512) { xl[i] = x[i]; hl[i] = hin[i]; cl[i] = cin[i]; }
  __syncthreads();
  int wave = tid >> 6, lane = tid & 63;
  int lr = wave >> 2;
  int g  = wave & 3;
  int j  = blockIdx.x * 2 + lr;
  int row = j + (g << 9);
  const float4* wi = (const float4*)(Wih + (size_t)row * HSZ);
  const float4* wh = (const float4*)(Whh + (size_t)row * HSZ);
  float4 wi0 = wi[lane], wi1 = wi[lane + 64], wh0 = wh[lane], wh1 = wh[lane + 64];
  float bb = bias[row];
#pragma unroll
  for (int b = 0; b < B; ++b) {
    float4 xv0 = ((const float4*)(xl + b * HSZ))[lane];
    float4 xv1 = ((const float4*)(xl + b * HSZ))[lane + 64];
    float4 hv0 = ((const float4*)(hl + b * HSZ))[lane];
    float4 hv1 = ((const float4*)(hl + b * HSZ))[lane + 64];
    float acc = dot4(wi0, xv0) + dot4(wi1, xv1) + dot4(wh0, hv0) + dot4(wh1, hv1);
    float z = wsum(acc) + bb;
    if (lane == 0) zl[(lr * 4 + g) * B + b] = z;
  }
  __syncthreads();
  for (int q = tid; q < 2 * B; q += 512) {
    int lr2 = q / B, b = q % B;
    int j2 = blockIdx.x * 2 + lr2;
    float z0 = zl[(lr2 * 4 + 0) * B + b], z1 = zl[(lr2 * 4 + 1) * B + b];
    float z2 = zl[(lr2 * 4 + 2) * B + b], z3 = zl[(lr2 * 4 + 3) * B + b];
    float c = sigf(z1) * cl[b * HSZ + j2] + sigf(z0) * tanhf(z2);
    cout[b * HSZ + j2] = c;
    hout[b * HSZ + j2] = sigf(z3) * tanhf(c);
  }
}

// FUSED attfeat (blocks 0..63) -> counter sync -> STAGGERED, DOUBLE-BUFFERED LDS sweep.
// Blocks 0..249 own 128 contiguous rows; block b starts at tile (b&7) to de-phase
// the HBM bursts. One barrier per tile; next tile's loads issued before compute.
template <int B>
__global__ void __launch_bounds__(512) k_atlg4(const float* __restrict__ h2,
                                               const float* __restrict__ enc,
                                               const float* __restrict__ Wc,
                                               const float* __restrict__ Wout,
                                               const float* __restrict__ bout,
                                               float* __restrict__ feat,
                                               float* __restrict__ pm, float* __restrict__ ps,
                                               float* __restrict__ pv, int* __restrict__ pi,
                                               int* __restrict__ cnt, int ep) {
  __shared__ float xs[BEAM * HSZ], at[BEAM * SEQ], xcs[BEAM * 1024];
  __shared__ float fst[BEAM * HSZ];
  __shared__ float tile[2 * 16 * HSZ];   // 64 KB double buffer
  int tid = threadIdx.x, wave = tid >> 6, lane = tid & 63;

  if (blockIdx.x < 64) {  // producer: attention + context + feat (verbatim r11-r15)
    for (int i = tid; i < B * HSZ; i += 512) xs[i] = h2[i];
    __syncthreads();
    if (tid < B * SEQ) {
      int b = tid >> 6, s2 = tid & 63;
      const float* er = enc + (s2 + 1) * HSZ;
      const float* xb = xs + b * HSZ;
      float acc = 0.f;
      for (int e = 0; e < HSZ; e += 4) {
        float4 ev = *(const float4*)(er + e);
        acc += ev.x * xb[e] + ev.y * xb[e + 1] + ev.z * xb[e + 2] + ev.w * xb[e + 3];
      }
      at[tid] = acc;
    }
    __syncthreads();
    if (tid < B) {
      float m = -INFINITY;
      for (int s2 = 0; s2 < SEQ; ++s2) m = fmaxf(m, at[tid * SEQ + s2]);
      float s = 0.f;
      for (int s2 = 0; s2 < SEQ; ++s2) { float e = expf(at[tid * SEQ + s2] - m); at[tid * SEQ + s2] = e; s += e; }
      float inv = 1.f / s;
      for (int s2 = 0; s2 < SEQ; ++s2) at[tid * SEQ + s2] *= inv;
    }
    __syncthreads();
    if (tid < 128) {
      int h4 = tid * 4;
      float4 acc[B];
#pragma unroll
      for (int b = 0; b < B; ++b) acc[b] = make_float4(0.f, 0.f, 0.f, 0.f);
      for (int s2 = 0; s2 < SEQ; ++s2) {
        float4 ev = *(const float4*)(enc + (s2 + 1) * HSZ + h4);
#pragma unroll
        for (int b = 0; b < B; ++b) {
          float a = at[b * SEQ + s2];
          acc[b].x += a * ev.x; acc[b].y += a * ev.y; acc[b].z += a * ev.z; acc[b].w += a * ev.w;
        }
      }
#pragma unroll
      for (int b = 0; b < B; ++b) *(float4*)(xcs + b * 1024 + 512 + h4) = acc[b];
    }
    for (int i = tid; i < B * HSZ; i += 512) {
      int b = i >> 9, hcol = i & 511;
      xcs[b * 1024 + hcol] = xs[b * HSZ + hcol];
    }
    __syncthreads();
    int j = blockIdx.x * 8 + wave;  // 0..511
    const float4* w = (const float4*)(Wc + (size_t)j * 1024);
    float4 w0 = w[lane], w1 = w[lane + 64], w2 = w[lane + 128], w3 = w[lane + 192];
#pragma unroll
    for (int b = 0; b < B; ++b) {
      const float4* xb = (const float4*)(xcs + b * 1024);
      float acc = dot4(w0, xb[lane]) + dot4(w1, xb[lane + 64]) +
                  dot4(w2, xb[lane + 128]) + dot4(w3, xb[lane + 192]);
      acc = wsum(acc);
      if (lane == 0) agst(&feat[b * HSZ + j], tanhf(acc));
    }
    __syncthreads();  // drains vmcnt: feat stores at coherence point
    if (tid == 0)
      __hip_atomic_fetch_add(cnt, 1, __ATOMIC_RELAXED, __HIP_MEMORY_SCOPE_AGENT);
  }

  // all blocks: single-thread backoff poll (r12/r14/r15-validated)
  if (tid == 0) {
    int target = ep * 64;
    long it = 0;
    while (agldi(cnt) < target && it < 50000000L) { __builtin_amdgcn_s_sleep(2); ++it; }
  }
  asm volatile("" ::: "memory");
  __syncthreads();

  for (int i = tid; i < B * HSZ; i += 512) fst[i] = agld(&feat[i]);
  __syncthreads();

  // per-beam feat fragments (r10 lane partition -> per-logit values bit-identical)
  float4 f0[B], f1[B];
#pragma unroll
  for (int b = 0; b < B; ++b) {
    f0[b] = ((const float4*)(fst + b * HSZ))[lane];
    f1[b] = ((const float4*)(fst + b * HSZ))[lane + 64];
  }
  float m[B], ss[B], tv[B][3];
  int tix[B][3];
#pragma unroll
  for (int b = 0; b < B; ++b) {
    m[b] = -INFINITY; ss[b] = 0.f;
#pragma unroll
    for (int k = 0; k < 3; ++k) { tv[b][k] = -INFINITY; tix[b][k] = 0x7fffffff; }
  }

  if (blockIdx.x < 250) {   // block-uniform branch
    int row0 = blockIdx.x * 128;
    int t0   = blockIdx.x & 7;   // stagger: de-phase HBM bursts across blocks
    // preload first tile
    const float4* g0p = (const float4*)(Wout + (size_t)(row0 + t0 * 16) * HSZ);
    float4 s0 = g0p[0 * 512 + tid];
    float4 s1 = g0p[1 * 512 + tid];
    float4 s2 = g0p[2 * 512 + tid];
    float4 s3 = g0p[3 * 512 + tid];
#pragma unroll 1
    for (int tt = 0; tt < 8; ++tt) {
      int t = (t0 + tt) & 7;
      float4* buf = (float4*)(tile + (tt & 1) * 16 * HSZ);
      buf[0 * 512 + tid] = s0;   // vmcnt drains here; latency hidden under prior compute
      buf[1 * 512 + tid] = s1;
      buf[2 * 512 + tid] = s2;
      buf[3 * 512 + tid] = s3;
      __syncthreads();           // tile visible; prior buffer's readers done (see note)
      if (tt < 7) {
        int tn = (t0 + tt + 1) & 7;
        const float4* gn = (const float4*)(Wout + (size_t)(row0 + tn * 16) * HSZ);
        s0 = gn[0 * 512 + tid];
        s1 = gn[1 * 512 + tid];
        s2 = gn[2 * 512 + tid];
        s3 = gn[3 * 512 + tid];
      }
      const float* bufr = tile + (tt & 1) * 16 * HSZ;
#pragma unroll
      for (int rr = 0; rr < 2; ++rr) {
        int rl  = wave * 2 + rr;          // 0..15
        int row = row0 + t * 16 + rl;
        const float4* wr = (const float4*)(bufr + rl * HSZ);
        float4 w0 = wr[lane], w1 = wr[lane + 64];
        float bo = bout[row];
#pragma unroll
        for (int b = 0; b < B; ++b) {
          float acc = wsum(dot4(w0, f0[b]) + dot4(w1, f1[b])) + bo;
          float mo = m[b], mn = fmaxf(mo, acc);
          ss[b] = (ss[b] == 0.f) ? expf(acc - mn) : ss[b] * expf(mo - mn) + expf(acc - mn);
          m[b]  = mn;
          ins3(tv[b], tix[b], acc, row);
        }
      }
      // buffer (tt&1) is rewritten at tt+2, after every wave passed barrier(tt+1),
      // which it reaches only after finishing this compute -> single barrier is safe.
    }
  }

  __shared__ float lm[8][3], lss[8][3], lv[8][3][3];
  __shared__ int li[8][3][3];
  if (lane == 0) {
#pragma unroll
    for (int b = 0; b < B; ++b) {
      lm[wave][b] = m[b]; lss[wave][b] = ss[b];
#pragma unroll
      for (int k = 0; k < 3; ++k) { lv[wave][b][k] = tv[b][k]; li[wave][b][k] = tix[b][k]; }
    }
  }
  __syncthreads();
  if (tid < B) {
    int b = tid;
    float M = -INFINITY;
#pragma unroll
    for (int w2 = 0; w2 < 8; ++w2) M = fmaxf(M, lm[w2][b]);
    float S = 0.f;
#pragma unroll
    for (int w2 = 0; w2 < 8; ++w2)
      S += (lss[w2][b] == 0.f) ? 0.f : lss[w2][b] * expf(lm[w2][b] - M);
    float bv[3] = {-INFINITY, -INFINITY, -INFINITY};
    int bi3[3]  = {0x7fffffff, 0x7fffffff, 0x7fffffff};
#pragma unroll
    for (int w2 = 0; w2 < 8; ++w2)
#pragma unroll
      for (int k = 0; k < 3; ++k) ins3(bv, bi3, lv[w2][b][k], li[w2][b][k]);
    int o = blockIdx.x * 3 + b;
    pm[o] = M; ps[o] = S;
#pragma unroll
    for (int k = 0; k < 3; ++k) { pv[o * 3 + k] = bv[k]; pi[o * 3 + k] = bi3[k]; }
  }
}

// tail: final merge over 256 partials + output write; 1 block x 256 (r14/r15 verbatim)
__global__ void __launch_bounds__(256) k_tail(const float* __restrict__ pm,
                                              const float* __restrict__ ps,
                                              const float* __restrict__ pv,
                                              const int* __restrict__ pi,
                                              const float* __restrict__ scores_rd,
                                              const int* __restrict__ tokens_rd,
                                              int* __restrict__ bt, int* __restrict__ outp) {
  const int ti = TMAX - 2;
  __shared__ float sM[3], sS[3], sV[3][3], sScore[3];
  __shared__ int sI[3][3], sOrig[3], sTokOld[3], sKstar;
  int tid = threadIdx.x, wave = tid >> 6, lane = tid & 63;
  if (wave < 3) {
    int b = wave;
    float lm4[4], ls4[4];
    float M = -INFINITY;
#pragma unroll
    for (int q = 0; q < 4; ++q) {
      int blk2 = lane + q * 64;
      lm4[q] = pm[blk2 * 3 + b]; ls4[q] = ps[blk2 * 3 + b];
      M = fmaxf(M, lm4[q]);
    }
#pragma unroll
    for (int off = 32; off; off >>= 1) M = fmaxf(M, __shfl_xor(M, off, 64));
    float S = 0.f;
#pragma unroll
    for (int q = 0; q < 4; ++q) S += (ls4[q] == 0.f) ? 0.f : ls4[q] * expf(lm4[q] - M);
    S = wsum(S);
    float bv[3] = {-INFINITY, -INFINITY, -INFINITY};
    int bi3[3]  = {0x7fffffff, 0x7fffffff, 0x7fffffff};
#pragma unroll
    for (int q = 0; q < 4; ++q) {
      int blk2 = lane + q * 64;
#pragma unroll
      for (int k = 0; k < 3; ++k)
        ins3(bv, bi3, pv[(blk2 * 3 + b) * 3 + k], pi[(blk2 * 3 + b) * 3 + k]);
    }
#pragma unroll
    for (int off = 32; off; off >>= 1) {
      float ov[3]; int oi[3];
#pragma unroll
      for (int k = 0; k < 3; ++k) { ov[k] = __shfl_xor(bv[k], off, 64); oi[k] = __shfl_xor(bi3[k], off, 64); }
#pragma unroll
      for (int k = 0; k < 3; ++k) ins3(bv, bi3, ov[k], oi[k]);
    }
    if (lane == 0) {
      sM[b] = M; sS[b] = S;
#pragma unroll
      for (int k = 0; k < 3; ++k) { sV[b][k] = bv[k]; sI[b][k] = bi3[k]; }
    }
  }
  __syncthreads();
  if (tid == 0) {
    float osc[3];
    for (int b = 0; b < 3; ++b) { osc[b] = scores_rd[b]; sTokOld[b] = tokens_rd[b]; }
    float cum[9];
    for (int b = 0; b < 3; ++b) {
      float o = osc[b] - sM[b] - logf(sS[b]);
      for (int k = 0; k < 3; ++k) cum[b * 3 + k] = sV[b][k] + o;
    }
    bool used[9] = {false, false, false, false, false, false, false, false, false};
    for (int k = 0; k < 3; ++k) {
      int bf = 0; float bb = -INFINITY;
      for (int f = 0; f < 9; ++f)
        if (!used[f] && cum[f] > bb) { bb = cum[f]; bf = f; }
      used[bf] = true;
      sScore[k] = bb;
      sOrig[k] = bf / 3;
    }
    float bb = -INFINITY; int kk = 0;
    for (int k = 0; k < 3; ++k) if (sScore[k] > bb) { bb = sScore[k]; kk = k; }
    sKstar = kk;
  }
  __syncthreads();
  const int* src = bt + (ti & 1) * (BEAM * TMAX);
  int* dst = bt + ((ti + 1) & 1) * (BEAM * TMAX);
  for (int idx = tid; idx < BEAM * TMAX; idx += 256) {
    int k = idx / TMAX, jj = idx % TMAX, o = sOrig[k];
    dst[idx] = (jj == ti + 1) ? sTokOld[o] : src[o * TMAX + jj];
  }
  __syncthreads();
  for (int jj = tid; jj < TMAX; jj += 256) outp[jj] = dst[sKstar * TMAX + jj];
}

extern "C" void kernel_launch(void* const* d_in, const int* in_sizes, int n_in,
                              void* d_out, int out_size, void* d_ws, size_t ws_size,
                              hipStream_t stream) {
  const int*   seq     = (const int*)d_in[0];
  const float* emb_enc = (const float*)d_in[1];
  const float* Wih_enc = (const float*)d_in[2];
  const float* Whh_enc = (const float*)d_in[3];
  const float* b_enc   = (const float*)d_in[4];
  const float* emb_dec = (const float*)d_in[5];
  const float* Wih_dec = (const float*)d_in[6];
  const float* Whh_dec = (const float*)d_in[7];
  const float* b_dec   = (const float*)d_in[8];
  const float* W_c     = (const float*)d_in[9];
  const float* W_out   = (const float*)d_in[10];
  const float* b_out   = (const float*)d_in[11];
  const int*   bosp    = (const int*)d_in[14];

  int* cnt = (int*)d_ws;                   // one counter line
  float* w = (float*)d_ws + FLS;
  float* xp1     = w; w += SEQ * H4;
  float* h1a     = w; w += (SEQ + 1) * HSZ;
  float* c1a     = w; w += (SEQ + 1) * HSZ;
  float* h2a     = w; w += (SEQ + 1) * HSZ;
  float* c2a     = w; w += (SEQ + 1) * HSZ;
  float* hdn1    = w; w += 2 * BEAM * HSZ;
  float* cdn1    = w; w += 2 * BEAM * HSZ;
  float* hdn2    = w; w += 2 * BEAM * HSZ;
  float* cdn2    = w; w += 2 * BEAM * HSZ;
  float* hd2p    = w; w += BEAM * HSZ;
  float* cd2p    = w; w += BEAM * HSZ;
  float* feat    = w; w += BEAM * HSZ;
  float* pm      = w; w += 256 * 3;
  float* ps      = w; w += 256 * 3;
  float* pv      = w; w += 256 * 3 * 3;
  float* sb      = w; w += 2 * 4;
  int* pi     = (int*)w; w += 256 * 3 * 3;
  int* tb     = (int*)w; w += 2 * 4;
  int* bt     = (int*)w; w += 2 * BEAM * TMAX + 4;
  int* outp   = (int*)d_out;

  hipMemsetAsync(cnt, 0, FLS * sizeof(int), stream);

  k_xw1<<<256, 512, 0, stream>>>(Wih_enc, b_enc, emb_enc, seq, xp1);
  for (int s = 0; s <= SEQ; ++s)
    k_encslot<<<256, 512, 0, stream>>>(Whh_enc, Wih_enc + LOFF, Whh_enc + LOFF, b_enc + H4,
                                       xp1, h1a, c1a, h2a, c2a, s);

  for (int s = 0; s < TMAX; ++s) {
    int rp = (s - 1) & 1, wp = s & 1;
    if (s == 0) {
      k_dcell1<1, 1, 0><<<256, 512, 0, stream>>>(
          Wih_dec, Whh_dec, b_dec, emb_dec, bosp,
          h1a + SEQ * HSZ, c1a + SEQ * HSZ, h2a + SEQ * HSZ, c2a + SEQ * HSZ,
          pm, ps, pv, pi,
          hdn1 + 0, cdn1 + 0, hd2p, cd2p,
          sb, sb, tb, tb, bt, 0);
      k_dcell2<1><<<256, 512, 0, stream>>>(Wih_dec + LOFF, Whh_dec + LOFF, b_dec + H4,
                                           hdn1 + 0, hd2p, cd2p, hdn2 + 0, cdn2 + 0);
      k_atlg4<1><<<256, 512, 0, stream>>>(hdn2 + 0, h2a, W_c, W_out, b_out, feat,
                                          pm, ps, pv, pi, cnt, s + 1);
    } else {
      float* h1p = hdn1 + rp * BEAM * HSZ; float* c1p = cdn1 + rp * BEAM * HSZ;
      float* h2p = hdn2 + rp * BEAM * HSZ; float* c2p = cdn2 + rp * BEAM * HSZ;
      float* h1o = hdn1 + wp * BEAM * HSZ; float* c1o = cdn1 + wp * BEAM * HSZ;
      float* h2o = hdn2 + wp * BEAM * HSZ; float* c2o = cdn2 + wp * BEAM * HSZ;
      if (s == 1)
        k_dcell1<3, 1, 1><<<256, 512, 0, stream>>>(
            Wih_dec, Whh_dec, b_dec, emb_dec, bosp,
            h1p, c1p, h2p, c2p, pm, ps, pv, pi,
            h1o, c1o, hd2p, cd2p,
            sb + rp * 4, sb + wp * 4, tb + rp * 4, tb + wp * 4, bt, -1);
      else
        k_dcell1<3, 3, 2><<<256, 512, 0, stream>>>(
            Wih_dec, Whh_dec, b_dec, emb_dec, bosp,
            h1p, c1p, h2p, c2p, pm, ps, pv, pi,
            h1o, c1o, hd2p, cd2p,
            sb + rp * 4, sb + wp * 4, tb + rp * 4, tb + wp * 4, bt, s - 2);
      k_dcell2<3><<<256, 512, 0, stream>>>(Wih_dec + LOFF, Whh_dec + LOFF, b_dec + H4,
                                           h1o, hd2p, cd2p, h2o, c2o);
      k_atlg4<3><<<256, 512, 0, stream>>>(h2o, h2a, W_c, W_out, b_out, feat,
                                          pm, ps, pv, pi, cnt, s + 1);
    }
  }
  k_tail<<<1, 256, 0, stream>>>(pm, ps, pv, pi, sb + 4, tb + 4, bt, outp);
}

// Round 17
// 3565.948 us; speedup vs baseline: 1.3786x; 1.0476x over previous
//
#include <hip/hip_runtime.h>
#include <math.h>

// Problem constants (fixed by the reference module)
#define HSZ   512
#define H4    2048
#define SEQ   64
#define VOC   32000
#define BEAM  3
#define TMAX  50
#define FLS   16   // flag line stride in ints (64 B)

#define LOFF  ((size_t)H4 * HSZ)   // per-layer weight stride

__device__ __forceinline__ float wsum(float v) {
#pragma unroll
  for (int off = 32; off; off >>= 1) v += __shfl_xor(v, off, 64);
  return v;
}
__device__ __forceinline__ float dot4(float4 a, float4 b) {
  return a.x * b.x + a.y * b.y + a.z * b.z + a.w * b.w;
}
__device__ __forceinline__ float sigf(float x) { return 1.f / (1.f + expf(-x)); }

__device__ __forceinline__ bool better(float v1, int i1, float v2, int i2) {
  return (v1 > v2) || (v1 == v2 && i1 < i2);  // jax.lax.top_k order: value desc, index asc
}
__device__ __forceinline__ void ins3(float* v, int* idx, float nv, int ni) {
  if (better(nv, ni, v[2], idx[2])) {
    if (better(nv, ni, v[1], idx[1])) {
      v[2] = v[1]; idx[2] = idx[1];
      if (better(nv, ni, v[0], idx[0])) { v[1] = v[0]; idx[1] = idx[0]; v[0] = nv; idx[0] = ni; }
      else { v[1] = nv; idx[1] = ni; }
    } else { v[2] = nv; idx[2] = ni; }
  }
}

// coherent accessors (agent scope, relaxed) — validated bit-exact in rounds 5-11
__device__ __forceinline__ float agld(const float* p) {
  return __hip_atomic_load(p, __ATOMIC_RELAXED, __HIP_MEMORY_SCOPE_AGENT);
}
__device__ __forceinline__ void agst(float* p, float v) {
  __hip_atomic_store(p, v, __ATOMIC_RELAXED, __HIP_MEMORY_SCOPE_AGENT);
}
__device__ __forceinline__ int agldi(const int* p) {
  return __hip_atomic_load(p, __ATOMIC_RELAXED, __HIP_MEMORY_SCOPE_AGENT);
}
__device__ __forceinline__ void agsti(int* p, int v) {
  __hip_atomic_store(p, v, __ATOMIC_RELAXED, __HIP_MEMORY_SCOPE_AGENT);
}

// ---------------- encoder ----------------

__global__ void __launch_bounds__(512) k_xw1(const float* __restrict__ Wih,
                                             const float* __restrict__ bias,
                                             const float* __restrict__ emb,
                                             const int* __restrict__ seq,
                                             float* __restrict__ xp1) {
  int t    = threadIdx.x & 63;
  int wave = threadIdx.x >> 6;
  int r    = blockIdx.x * 8 + wave;
  int tok  = seq[t];
  const float* xr = emb + (size_t)tok * HSZ;
  const float* wr = Wih + (size_t)r * HSZ;
  float acc = 0.f;
  for (int e = 0; e < HSZ; e += 4) {
    float4 wv = *(const float4*)(wr + e);
    float4 xv = *(const float4*)(xr + e);
    acc += dot4(wv, xv);
  }
  xp1[t * H4 + r] = acc + bias[r];
}

__global__ void __launch_bounds__(512) k_encslot(const float* __restrict__ Whh1,
                                                 const float* __restrict__ Wih2,
                                                 const float* __restrict__ Whh2,
                                                 const float* __restrict__ b2,
                                                 const float* __restrict__ xp1,
                                                 float* __restrict__ h1a, float* __restrict__ c1a,
                                                 float* __restrict__ h2a, float* __restrict__ c2a,
                                                 int s) {
  __shared__ float rowX[HSZ], rowH[HSZ], zl[16];
  int tid = threadIdx.x, wave = tid >> 6, lane = tid & 63;
  bool l2 = blockIdx.x >= 128;
  int t = l2 ? s - 1 : s;
  if (t < 0 || t >= SEQ) return;
  int bb = blockIdx.x & 127;
  int lr = wave >> 1;
  int j  = bb * 4 + lr;
  int g0 = (wave & 1) * 2;
  if (!l2) {
    rowX[tid] = (t > 0) ? h1a[t * HSZ + tid] : 0.f;
    __syncthreads();
    float4 h0 = ((const float4*)rowX)[lane], h1v = ((const float4*)rowX)[lane + 64];
#pragma unroll
    for (int gg = 0; gg < 2; ++gg) {
      int g = g0 + gg;
      int row = j + (g << 9);
      const float4* wr = (const float4*)(Whh1 + (size_t)row * HSZ);
      float zs = wsum(dot4(wr[lane], h0) + dot4(wr[lane + 64], h1v));
      if (lane == 0) zl[lr * 4 + g] = zs + xp1[t * H4 + row];
    }
    __syncthreads();
    if (tid < 4) {
      int j2 = bb * 4 + tid;
      float z0 = zl[tid * 4 + 0], z1 = zl[tid * 4 + 1], z2 = zl[tid * 4 + 2], z3 = zl[tid * 4 + 3];
      float cp = (t > 0) ? c1a[t * HSZ + j2] : 0.f;
      float c = sigf(z1) * cp + sigf(z0) * tanhf(z2);
      c1a[(t + 1) * HSZ + j2] = c;
      h1a[(t + 1) * HSZ + j2] = sigf(z3) * tanhf(c);
    }
  } else {
    rowX[tid] = h1a[(t + 1) * HSZ + tid];
    rowH[tid] = (t > 0) ? h2a[t * HSZ + tid] : 0.f;
    __syncthreads();
    float4 x0 = ((const float4*)rowX)[lane], x1 = ((const float4*)rowX)[lane + 64];
    float4 h0 = ((const float4*)rowH)[lane], h1v = ((const float4*)rowH)[lane + 64];
#pragma unroll
    for (int gg = 0; gg < 2; ++gg) {
      int g = g0 + gg;
      int row = j + (g << 9);
      const float4* wi = (const float4*)(Wih2 + (size_t)row * HSZ);
      const float4* wh = (const float4*)(Whh2 + (size_t)row * HSZ);
      float zs = wsum(dot4(wi[lane], x0) + dot4(wi[lane + 64], x1) +
                      dot4(wh[lane], h0) + dot4(wh[lane + 64], h1v));
      if (lane == 0) zl[lr * 4 + g] = zs + b2[row];
    }
    __syncthreads();
    if (tid < 4) {
      int j2 = bb * 4 + tid;
      float z0 = zl[tid * 4 + 0], z1 = zl[tid * 4 + 1], z2 = zl[tid * 4 + 2], z3 = zl[tid * 4 + 3];
      float cp = (t > 0) ? c2a[t * HSZ + j2] : 0.f;
      float c = sigf(z1) * cp + sigf(z0) * tanhf(z2);
      c2a[(t + 1) * HSZ + j2] = c;
      h2a[(t + 1) * HSZ + j2] = sigf(z3) * tanhf(c);
    }
  }
}

// ---------------- decoder ----------------

// Layer-1 cell with FUSED beam merge (round-10/11, passed bit-exact).
template <int B, int BIN, int MODE>
__global__ void __launch_bounds__(512) k_dcell1(
    const float* __restrict__ Wih, const float* __restrict__ Whh,
    const float* __restrict__ bias,
    const float* __restrict__ emb_dec, const int* __restrict__ bosp,
    const float* __restrict__ h1prev, const float* __restrict__ c1prev,
    const float* __restrict__ h2prev, const float* __restrict__ c2prev,
    const float* __restrict__ pm, const float* __restrict__ ps,
    const float* __restrict__ pv, const int* __restrict__ pi,
    float* __restrict__ hout, float* __restrict__ cout,
    float* __restrict__ hd2p, float* __restrict__ cd2p,
    const float* __restrict__ scores_rd, float* __restrict__ scores_wr,
    const int* __restrict__ tokens_rd, int* __restrict__ tokens_wr,
    int* __restrict__ bt, int ti) {
  __shared__ float xl[B * HSZ], hl[B * HSZ], cl[B * HSZ], zl[8 * B];
  __shared__ float sM[3], sS[3], sV[3][3], sScore[3];
  __shared__ int sI[3][3], sOrig[3], sTokNew[3], sTokOld[3];
  int tid = threadIdx.x, wave = tid >> 6, lane = tid & 63;

  if (MODE >= 1) {
    if (wave < BIN) {
      int b = wave;
      float lm4[4], ls4[4];
      float M = -INFINITY;
#pragma unroll
      for (int q = 0; q < 4; ++q) {
        int blk2 = lane + q * 64;
        lm4[q] = pm[blk2 * 3 + b]; ls4[q] = ps[blk2 * 3 + b];
        M = fmaxf(M, lm4[q]);
      }
#pragma unroll
      for (int off = 32; off; off >>= 1) M = fmaxf(M, __shfl_xor(M, off, 64));
      float S = 0.f;
#pragma unroll
      for (int q = 0; q < 4; ++q) S += ls4[q] * expf(lm4[q] - M);
      S = wsum(S);
      float bv[3] = {-INFINITY, -INFINITY, -INFINITY};
      int bi3[3]  = {0x7fffffff, 0x7fffffff, 0x7fffffff};
#pragma unroll
      for (int q = 0; q < 4; ++q) {
        int blk2 = lane + q * 64;
#pragma unroll
        for (int k = 0; k < 3; ++k)
          ins3(bv, bi3, pv[(blk2 * 3 + b) * 3 + k], pi[(blk2 * 3 + b) * 3 + k]);
      }
#pragma unroll
      for (int off = 32; off; off >>= 1) {
        float ov[3]; int oi[3];
#pragma unroll
        for (int k = 0; k < 3; ++k) { ov[k] = __shfl_xor(bv[k], off, 64); oi[k] = __shfl_xor(bi3[k], off, 64); }
#pragma unroll
        for (int k = 0; k < 3; ++k) ins3(bv, bi3, ov[k], oi[k]);
      }
      if (lane == 0) {
        sM[b] = M; sS[b] = S;
#pragma unroll
        for (int k = 0; k < 3; ++k) { sV[b][k] = bv[k]; sI[b][k] = bi3[k]; }
      }
    }
    __syncthreads();
    if (tid == 0) {
      if (MODE == 1) {
        float off0 = -sM[0] - logf(sS[0]);
        for (int k = 0; k < 3; ++k) {
          sScore[k] = sV[0][k] + off0;
          sTokNew[k] = sI[0][k]; sOrig[k] = 0; sTokOld[k] = 0;
        }
      } else {
        float osc[3];
        for (int b = 0; b < 3; ++b) { osc[b] = scores_rd[b]; sTokOld[b] = tokens_rd[b]; }
        float cum[9];
        for (int b = 0; b < 3; ++b) {
          float o = osc[b] - sM[b] - logf(sS[b]);
          for (int k = 0; k < 3; ++k) cum[b * 3 + k] = sV[b][k] + o;
        }
        bool used[9] = {false, false, false, false, false, false, false, false, false};
        for (int k = 0; k < 3; ++k) {
          int bf = 0; float bb = -INFINITY;
          for (int f = 0; f < 9; ++f)
            if (!used[f] && cum[f] > bb) { bb = cum[f]; bf = f; }  // strict >: lowest flat idx on tie
          used[bf] = true;
          sScore[k] = bb;
          int ob = bf / 3;
          sOrig[k] = ob;
          sTokNew[k] = sI[ob][bf - ob * 3];
        }
      }
    }
    __syncthreads();
  }

  if (MODE == 0) {
    int bos = bosp[0];
    for (int i = tid; i < B * HSZ; i += 512) {
      xl[i] = emb_dec[(size_t)bos * HSZ + i];
      hl[i] = h1prev[i]; cl[i] = c1prev[i];
    }
    if (blockIdx.x == 0) {
      for (int i = tid; i < B * HSZ; i += 512) { hd2p[i] = h2prev[i]; cd2p[i] = c2prev[i]; }
    }
  } else {
    for (int i = tid; i < B * HSZ; i += 512) {
      int b = i >> 9, e = i & 511;
      xl[i] = emb_dec[(size_t)sTokNew[b] * HSZ + e];
      hl[i] = h1prev[sOrig[b] * HSZ + e];
      cl[i] = c1prev[sOrig[b] * HSZ + e];
    }
    if (blockIdx.x == 0) {
      for (int i = tid; i < B * HSZ; i += 512) {
        int b = i >> 9, e = i & 511;
        hd2p[i] = h2prev[sOrig[b] * HSZ + e];
        cd2p[i] = c2prev[sOrig[b] * HSZ + e];
      }
      if (MODE == 1) {
        int bos = bosp[0];
        for (int idx = tid; idx < BEAM * TMAX; idx += 512) bt[idx] = bos;  // buffer 0
      } else {
        const int* src = bt + (ti & 1) * (BEAM * TMAX);
        int* dst = bt + ((ti + 1) & 1) * (BEAM * TMAX);
        for (int idx = tid; idx < BEAM * TMAX; idx += 512) {
          int k = idx / TMAX, jj = idx % TMAX, o = sOrig[k];
          dst[idx] = (jj == ti + 1) ? sTokOld[o] : src[o * TMAX + jj];
        }
      }
      if (tid < 3) { scores_wr[tid] = sScore[tid]; tokens_wr[tid] = sTokNew[tid]; }
    }
  }
  __syncthreads();

  int lr = wave >> 2;
  int g  = wave & 3;
  int j  = blockIdx.x * 2 + lr;
  int row = j + (g << 9);
  const float4* wi = (const float4*)(Wih + (size_t)row * HSZ);
  const float4* wh = (const float4*)(Whh + (size_t)row * HSZ);
  float4 wi0 = wi[lane], wi1 = wi[lane + 64], wh0 = wh[lane], wh1 = wh[lane + 64];
  float bb = bias[row];
#pragma unroll
  for (int b = 0; b < B; ++b) {
    float4 xv0 = ((const float4*)(xl + b * HSZ))[lane];
    float4 xv1 = ((const float4*)(xl + b * HSZ))[lane + 64];
    float4 hv0 = ((const float4*)(hl + b * HSZ))[lane];
    float4 hv1 = ((const float4*)(hl + b * HSZ))[lane + 64];
    float acc = dot4(wi0, xv0) + dot4(wi1, xv1) + dot4(wh0, hv0) + dot4(wh1, hv1);
    float z = wsum(acc) + bb;
    if (lane == 0) zl[(lr * 4 + g) * B + b] = z;
  }
  __syncthreads();
  for (int q = tid; q < 2 * B; q += 512) {
    int lr2 = q / B, b = q % B;
    int j2 = blockIdx.x * 2 + lr2;
    float z0 = zl[(lr2 * 4 + 0) * B + b], z1 = zl[(lr2 * 4 + 1) * B + b];
    float z2 = zl[(lr2 * 4 + 2) * B + b], z3 = zl[(lr2 * 4 + 3) * B + b];
    float c = sigf(z1) * cl[b * HSZ + j2] + sigf(z0) * tanhf(z2);
    cout[b * HSZ + j2] = c;
    hout[b * HSZ + j2] = sigf(z3) * tanhf(c);
  }
}

// layer-2 cell
template <int B>
__global__ void __launch_bounds__(512) k_dcell2(const float* __restrict__ Wih,
                                                const float* __restrict__ Whh,
                                                const float* __restrict__ bias,
                                                const float* __restrict__ x,
                                                const float* __restrict__ hin,
                                                const float* __restrict__ cin,
                                                float* __restrict__ hout, float* __restrict__ cout) {
  __shared__ float xl[B * HSZ], hl[B * HSZ], cl[B * HSZ], zl[8 * B];
  int tid = threadIdx.x;
  for (int i = tid; i < B * HSZ; i += 512) { xl[i] = x[i]; hl[i] = hin[i]; cl[i] = cin[i]; }
  __syncthreads();
  int wave = tid >> 6, lane = tid & 63;
  int lr = wave >> 2;
  int g  = wave & 3;
  int j  = blockIdx.x * 2 + lr;
  int row = j + (g << 9);
  const float4* wi = (const float4*)(Wih + (size_t)row * HSZ);
  const float4* wh = (const float4*)(Whh + (size_t)row * HSZ);
  float4 wi0 = wi[lane], wi1 = wi[lane + 64], wh0 = wh[lane], wh1 = wh[lane + 64];
  float bb = bias[row];
#pragma unroll
  for (int b = 0; b < B; ++b) {
    float4 xv0 = ((const float4*)(xl + b * HSZ))[lane];
    float4 xv1 = ((const float4*)(xl + b * HSZ))[lane + 64];
    float4 hv0 = ((const float4*)(hl + b * HSZ))[lane];
    float4 hv1 = ((const float4*)(hl + b * HSZ))[lane + 64];
    float acc = dot4(wi0, xv0) + dot4(wi1, xv1) + dot4(wh0, hv0) + dot4(wh1, hv1);
    float z = wsum(acc) + bb;
    if (lane == 0) zl[(lr * 4 + g) * B + b] = z;
  }
  __syncthreads();
  for (int q = tid; q < 2 * B; q += 512) {
    int lr2 = q / B, b = q % B;
    int j2 = blockIdx.x * 2 + lr2;
    float z0 = zl[(lr2 * 4 + 0) * B + b], z1 = zl[(lr2 * 4 + 1) * B + b];
    float z2 = zl[(lr2 * 4 + 2) * B + b], z3 = zl[(lr2 * 4 + 3) * B + b];
    float c = sigf(z1) * cl[b * HSZ + j2] + sigf(z0) * tanhf(z2);
    cout[b * HSZ + j2] = c;
    hout[b * HSZ + j2] = sigf(z3) * tanhf(c);
  }
}

// FUSED attention+feat (blocks 0..63 produce) -> flag sync -> logits (all 256 blocks).
// attfeat and logits math verbatim from round 10 (bit-exact twice).
template <int B>
__global__ void __launch_bounds__(512) k_atlg(const float* __restrict__ h2,
                                              const float* __restrict__ enc,
                                              const float* __restrict__ Wc,
                                              const float* __restrict__ Wout,
                                              const float* __restrict__ bout,
                                              float* __restrict__ feat,
                                              float* __restrict__ pm, float* __restrict__ ps,
                                              float* __restrict__ pv, int* __restrict__ pi,
                                              int* __restrict__ flags, int ep) {
  __shared__ float xs[BEAM * HSZ], at[BEAM * SEQ], xcs[BEAM * 1024];
  __shared__ float fst[BEAM * HSZ];
  int tid = threadIdx.x, wave = tid >> 6, lane = tid & 63;

  if (blockIdx.x < 64) {  // producer: attention + context + feat (verbatim)
    for (int i = tid; i < B * HSZ; i += 512) xs[i] = h2[i];
    __syncthreads();
    if (tid < B * SEQ) {
      int b = tid >> 6, s2 = tid & 63;
      const float* er = enc + (s2 + 1) * HSZ;
      const float* xb = xs + b * HSZ;
      float acc = 0.f;
      for (int e = 0; e < HSZ; e += 4) {
        float4 ev = *(const float4*)(er + e);
        acc += ev.x * xb[e] + ev.y * xb[e + 1] + ev.z * xb[e + 2] + ev.w * xb[e + 3];
      }
      at[tid] = acc;
    }
    __syncthreads();
    if (tid < B) {
      float m = -INFINITY;
      for (int s2 = 0; s2 < SEQ; ++s2) m = fmaxf(m, at[tid * SEQ + s2]);
      float s = 0.f;
      for (int s2 = 0; s2 < SEQ; ++s2) { float e = expf(at[tid * SEQ + s2] - m); at[tid * SEQ + s2] = e; s += e; }
      float inv = 1.f / s;
      for (int s2 = 0; s2 < SEQ; ++s2) at[tid * SEQ + s2] *= inv;
    }
    __syncthreads();
    if (tid < 128) {
      int h4 = tid * 4;
      float4 acc[B];
#pragma unroll
      for (int b = 0; b < B; ++b) acc[b] = make_float4(0.f, 0.f, 0.f, 0.f);
      for (int s2 = 0; s2 < SEQ; ++s2) {
        float4 ev = *(const float4*)(enc + (s2 + 1) * HSZ + h4);
#pragma unroll
        for (int b = 0; b < B; ++b) {
          float a = at[b * SEQ + s2];
          acc[b].x += a * ev.x; acc[b].y += a * ev.y; acc[b].z += a * ev.z; acc[b].w += a * ev.w;
        }
      }
#pragma unroll
      for (int b = 0; b < B; ++b) *(float4*)(xcs + b * 1024 + 512 + h4) = acc[b];
    }
    for (int i = tid; i < B * HSZ; i += 512) {
      int b = i >> 9, hcol = i & 511;
      xcs[b * 1024 + hcol] = xs[b * HSZ + hcol];
    }
    __syncthreads();
    int j = blockIdx.x * 8 + wave;  // 0..511
    const float4* w = (const float4*)(Wc + (size_t)j * 1024);
    float4 w0 = w[lane], w1 = w[lane + 64], w2 = w[lane + 128], w3 = w[lane + 192];
#pragma unroll
    for (int b = 0; b < B; ++b) {
      const float4* xb = (const float4*)(xcs + b * 1024);
      float acc = dot4(w0, xb[lane]) + dot4(w1, xb[lane + 64]) +
                  dot4(w2, xb[lane + 128]) + dot4(w3, xb[lane + 192]);
      acc = wsum(acc);
      if (lane == 0) agst(&feat[b * HSZ + j], tanhf(acc));
    }
    __syncthreads();  // drains vmcnt: feat stores at coherence point
    if (tid == 0) agsti(&flags[blockIdx.x * FLS], ep);
  }

  // all blocks: wait for the 64 producer flags (parallel poll, r8-validated pattern)
  if (tid < 64) {
    long it = 0;
    while (agldi(&flags[tid * FLS]) < ep && it < 200000000L) ++it;  // bailout beats a hang
  }
  asm volatile("" ::: "memory");
  __syncthreads();

  // logits (verbatim, feat via coherent loads)
  for (int i = tid; i < B * HSZ; i += 512) fst[i] = agld(&feat[i]);
  __syncthreads();
  int gid = blockIdx.x * 8 + wave;  // 0..2047
  float4 f0[B], f1[B];
#pragma unroll
  for (int b = 0; b < B; ++b) {
    f0[b] = ((const float4*)(fst + b * HSZ))[lane];
    f1[b] = ((const float4*)(fst + b * HSZ))[lane + 64];
  }
  float m[B], ss[B], tv[B][3];
  int tix[B][3];
#pragma unroll
  for (int b = 0; b < B; ++b) {
    m[b] = -INFINITY; ss[b] = 0.f;
#pragma unroll
    for (int k = 0; k < 3; ++k) { tv[b][k] = -INFINITY; tix[b][k] = 0x7fffffff; }
  }
  for (int k0 = 0; k0 < 16; k0 += 8) {
    float4 a0[8], a1[8]; float ab[8]; int vr[8];
#pragma unroll
    for (int u = 0; u < 8; ++u) {
      int v = gid + (k0 + u) * 2048;
      vr[u] = v;
      if (v < VOC) {
        const float4* wr = (const float4*)(Wout + (size_t)v * HSZ);
        a0[u] = wr[lane]; a1[u] = wr[lane + 64]; ab[u] = bout[v];
      } else {
        a0[u] = make_float4(0.f, 0.f, 0.f, 0.f); a1[u] = a0[u]; ab[u] = 0.f;
      }
    }
#pragma unroll
    for (int u = 0; u < 8; ++u) {
      if (vr[u] >= VOC) continue;  // wave-uniform
#pragma unroll
      for (int b = 0; b < B; ++b) {
        float acc = wsum(dot4(a0[u], f0[b]) + dot4(a1[u], f1[b])) + ab[u];
        float mo = m[b], mn = fmaxf(mo, acc);
        ss[b] = ss[b] * expf(mo - mn) + expf(acc - mn);
        m[b]  = mn;
        ins3(tv[b], tix[b], acc, vr[u]);
      }
    }
  }
  __shared__ float lm[8][3], lss[8][3], lv[8][3][3];
  __shared__ int li[8][3][3];
  if (lane == 0) {
#pragma unroll
    for (int b = 0; b < B; ++b) {
      lm[wave][b] = m[b]; lss[wave][b] = ss[b];
#pragma unroll
      for (int k = 0; k < 3; ++k) { lv[wave][b][k] = tv[b][k]; li[wave][b][k] = tix[b][k]; }
    }
  }
  __syncthreads();
  if (tid < B) {
    int b = tid;
    float M = -INFINITY;
#pragma unroll
    for (int w2 = 0; w2 < 8; ++w2) M = fmaxf(M, lm[w2][b]);
    float S = 0.f;
#pragma unroll
    for (int w2 = 0; w2 < 8; ++w2) S += lss[w2][b] * expf(lm[w2][b] - M);
    float bv[3] = {-INFINITY, -INFINITY, -INFINITY};
    int bi3[3]  = {0x7fffffff, 0x7fffffff, 0x7fffffff};
#pragma unroll
    for (int w2 = 0; w2 < 8; ++w2)
#pragma unroll
      for (int k = 0; k < 3; ++k) ins3(bv, bi3, lv[w2][b][k], li[w2][b][k]);
    int o = blockIdx.x * 3 + b;
    pm[o] = M; ps[o] = S;
#pragma unroll
    for (int k = 0; k < 3; ++k) { pv[o * 3 + k] = bv[k]; pi[o * 3 + k] = bi3[k]; }
  }
}

// tail: final merge + output write; 1 block x 256
__global__ void __launch_bounds__(256) k_tail(const float* __restrict__ pm,
                                              const float* __restrict__ ps,
                                              const float* __restrict__ pv,
                                              const int* __restrict__ pi,
                                              const float* __restrict__ scores_rd,
                                              const int* __restrict__ tokens_rd,
                                              int* __restrict__ bt, int* __restrict__ outp) {
  const int ti = TMAX - 2;
  __shared__ float sM[3], sS[3], sV[3][3], sScore[3];
  __shared__ int sI[3][3], sOrig[3], sTokOld[3], sKstar;
  int tid = threadIdx.x, wave = tid >> 6, lane = tid & 63;
  if (wave < 3) {
    int b = wave;
    float lm4[4], ls4[4];
    float M = -INFINITY;
#pragma unroll
    for (int q = 0; q < 4; ++q) {
      int blk2 = lane + q * 64;
      lm4[q] = pm[blk2 * 3 + b]; ls4[q] = ps[blk2 * 3 + b];
      M = fmaxf(M, lm4[q]);
    }
#pragma unroll
    for (int off = 32; off; off >>= 1) M = fmaxf(M, __shfl_xor(M, off, 64));
    float S = 0.f;
#pragma unroll
    for (int q = 0; q < 4; ++q) S += ls4[q] * expf(lm4[q] - M);
    S = wsum(S);
    float bv[3] = {-INFINITY, -INFINITY, -INFINITY};
    int bi3[3]  = {0x7fffffff, 0x7fffffff, 0x7fffffff};
#pragma unroll
    for (int q = 0; q < 4; ++q) {
      int blk2 = lane + q * 64;
#pragma unroll
      for (int k = 0; k < 3; ++k)
        ins3(bv, bi3, pv[(blk2 * 3 + b) * 3 + k], pi[(blk2 * 3 + b) * 3 + k]);
    }
#pragma unroll
    for (int off = 32; off; off >>= 1) {
      float ov[3]; int oi[3];
#pragma unroll
      for (int k = 0; k < 3; ++k) { ov[k] = __shfl_xor(bv[k], off, 64); oi[k] = __shfl_xor(bi3[k], off, 64); }
#pragma unroll
      for (int k = 0; k < 3; ++k) ins3(bv, bi3, ov[k], oi[k]);
    }
    if (lane == 0) {
      sM[b] = M; sS[b] = S;
#pragma unroll
      for (int k = 0; k < 3; ++k) { sV[b][k] = bv[k]; sI[b][k] = bi3[k]; }
    }
  }
  __syncthreads();
  if (tid == 0) {
    float osc[3];
    for (int b = 0; b < 3; ++b) { osc[b] = scores_rd[b]; sTokOld[b] = tokens_rd[b]; }
    float cum[9];
    for (int b = 0; b < 3; ++b) {
      float o = osc[b] - sM[b] - logf(sS[b]);
      for (int k = 0; k < 3; ++k) cum[b * 3 + k] = sV[b][k] + o;
    }
    bool used[9] = {false, false, false, false, false, false, false, false, false};
    for (int k = 0; k < 3; ++k) {
      int bf = 0; float bb = -INFINITY;
      for (int f = 0; f < 9; ++f)
        if (!used[f] && cum[f] > bb) { bb = cum[f]; bf = f; }
      used[bf] = true;
      sScore[k] = bb;
      sOrig[k] = bf / 3;
    }
    float bb = -INFINITY; int kk = 0;
    for (int k = 0; k < 3; ++k) if (sScore[k] > bb) { bb = sScore[k]; kk = k; }
    sKstar = kk;
  }
  __syncthreads();
  const int* src = bt + (ti & 1) * (BEAM * TMAX);
  int* dst = bt + ((ti + 1) & 1) * (BEAM * TMAX);
  for (int idx = tid; idx < BEAM * TMAX; idx += 256) {
    int k = idx / TMAX, jj = idx % TMAX, o = sOrig[k];
    dst[idx] = (jj == ti + 1) ? sTokOld[o] : src[o * TMAX + jj];
  }
  __syncthreads();
  for (int jj = tid; jj < TMAX; jj += 256) outp[jj] = dst[sKstar * TMAX + jj];
}

extern "C" void kernel_launch(void* const* d_in, const int* in_sizes, int n_in,
                              void* d_out, int out_size, void* d_ws, size_t ws_size,
                              hipStream_t stream) {
  const int*   seq     = (const int*)d_in[0];
  const float* emb_enc = (const float*)d_in[1];
  const float* Wih_enc = (const float*)d_in[2];
  const float* Whh_enc = (const float*)d_in[3];
  const float* b_enc   = (const float*)d_in[4];
  const float* emb_dec = (const float*)d_in[5];
  const float* Wih_dec = (const float*)d_in[6];
  const float* Whh_dec = (const float*)d_in[7];
  const float* b_dec   = (const float*)d_in[8];
  const float* W_c     = (const float*)d_in[9];
  const float* W_out   = (const float*)d_in[10];
  const float* b_out   = (const float*)d_in[11];
  const int*   bosp    = (const int*)d_in[14];

  int* flags = (int*)d_ws;                 // 64 lines x 64 B
  float* w = (float*)d_ws + 64 * FLS;
  float* xp1     = w; w += SEQ * H4;
  float* h1a     = w; w += (SEQ + 1) * HSZ;
  float* c1a     = w; w += (SEQ + 1) * HSZ;
  float* h2a     = w; w += (SEQ + 1) * HSZ;
  float* c2a     = w; w += (SEQ + 1) * HSZ;
  float* hdn1    = w; w += 2 * BEAM * HSZ;
  float* cdn1    = w; w += 2 * BEAM * HSZ;
  float* hdn2    = w; w += 2 * BEAM * HSZ;
  float* cdn2    = w; w += 2 * BEAM * HSZ;
  float* hd2p    = w; w += BEAM * HSZ;
  float* cd2p    = w; w += BEAM * HSZ;
  float* feat    = w; w += BEAM * HSZ;
  float* pm      = w; w += 256 * 3;
  float* ps      = w; w += 256 * 3;
  float* pv      = w; w += 256 * 3 * 3;
  float* sb      = w; w += 2 * 4;
  int* pi     = (int*)w; w += 256 * 3 * 3;
  int* tb     = (int*)w; w += 2 * 4;
  int* bt     = (int*)w; w += 2 * BEAM * TMAX + 4;
  int* outp   = (int*)d_out;

  hipMemsetAsync(flags, 0, 64 * FLS * sizeof(int), stream);

  k_xw1<<<256, 512, 0, stream>>>(Wih_enc, b_enc, emb_enc, seq, xp1);
  for (int s = 0; s <= SEQ; ++s)
    k_encslot<<<256, 512, 0, stream>>>(Whh_enc, Wih_enc + LOFF, Whh_enc + LOFF, b_enc + H4,
                                       xp1, h1a, c1a, h2a, c2a, s);

  for (int s = 0; s < TMAX; ++s) {
    int rp = (s - 1) & 1, wp = s & 1;
    if (s == 0) {
      k_dcell1<1, 1, 0><<<256, 512, 0, stream>>>(
          Wih_dec, Whh_dec, b_dec, emb_dec, bosp,
          h1a + SEQ * HSZ, c1a + SEQ * HSZ, h2a + SEQ * HSZ, c2a + SEQ * HSZ,
          pm, ps, pv, pi,
          hdn1 + 0, cdn1 + 0, hd2p, cd2p,
          sb, sb, tb, tb, bt, 0);
      k_dcell2<1><<<256, 512, 0, stream>>>(Wih_dec + LOFF, Whh_dec + LOFF, b_dec + H4,
                                           hdn1 + 0, hd2p, cd2p, hdn2 + 0, cdn2 + 0);
      k_atlg<1><<<256, 512, 0, stream>>>(hdn2 + 0, h2a, W_c, W_out, b_out, feat,
                                         pm, ps, pv, pi, flags, s + 1);
    } else {
      float* h1p = hdn1 + rp * BEAM * HSZ; float* c1p = cdn1 + rp * BEAM * HSZ;
      float* h2p = hdn2 + rp * BEAM * HSZ; float* c2p = cdn2 + rp * BEAM * HSZ;
      float* h1o = hdn1 + wp * BEAM * HSZ; float* c1o = cdn1 + wp * BEAM * HSZ;
      float* h2o = hdn2 + wp * BEAM * HSZ; float* c2o = cdn2 + wp * BEAM * HSZ;
      if (s == 1)
        k_dcell1<3, 1, 1><<<256, 512, 0, stream>>>(
            Wih_dec, Whh_dec, b_dec, emb_dec, bosp,
            h1p, c1p, h2p, c2p, pm, ps, pv, pi,
            h1o, c1o, hd2p, cd2p,
            sb + rp * 4, sb + wp * 4, tb + rp * 4, tb + wp * 4, bt, -1);
      else
        k_dcell1<3, 3, 2><<<256, 512, 0, stream>>>(
            Wih_dec, Whh_dec, b_dec, emb_dec, bosp,
            h1p, c1p, h2p, c2p, pm, ps, pv, pi,
            h1o, c1o, hd2p, cd2p,
            sb + rp * 4, sb + wp * 4, tb + rp * 4, tb + wp * 4, bt, s - 2);
      k_dcell2<3><<<256, 512, 0, stream>>>(Wih_dec + LOFF, Whh_dec + LOFF, b_dec + H4,
                                           h1o, hd2p, cd2p, h2o, c2o);
      k_atlg<3><<<256, 512, 0, stream>>>(h2o, h2a, W_c, W_out, b_out, feat,
                                         pm, ps, pv, pi, flags, s + 1);
    }
  }
  k_tail<<<1, 256, 0, stream>>>(pm, ps, pv, pi, sb + 4, tb + 4, bt, outp);
}